// Round 13
// baseline (2094.706 us; speedup 1.0000x reference)
//
#include <hip/hip_runtime.h>
#include <math.h>

#define N_NODES 50000
#define N_EDGES 800000
#define HID 64
#define HEADS 4
#define HC 256
#define NEG_SLOPE 0.2f
#define LN_EPS 1e-5f

typedef __attribute__((ext_vector_type(8))) short bf16x8;
typedef __attribute__((ext_vector_type(8))) unsigned short u16x8;
typedef __attribute__((ext_vector_type(4))) float f32x4;

__device__ __forceinline__ float bf2f(unsigned short u) {
    return __uint_as_float(((unsigned int)u) << 16);
}
__device__ __forceinline__ unsigned short f2bf(float f) {
    unsigned int u = __float_as_uint(f);
    u = (u + 0x7fffu + ((u >> 16) & 1u)) >> 16;   // RNE
    return (unsigned short)u;
}
__device__ __forceinline__ float fast_tanh(float v) {
    const float c = fminf(fmaxf(v, -15.f), 15.f);
    const float e = __expf(2.f * c);
    return 1.f - 2.f / (e + 1.f);
}

// ---------------- K1: node transform -> TRANSPOSED-TILED bf16 xl_t / xr_t --
// xl_t[node][pos], pos = (c&15)*16 + (c>>4) for channel c. Lane(arow) then
// reads channels {nt*16+arow : nt=0..15} as 16 contiguous ushorts.
__global__ __launch_bounds__(256) void k_node_transform(
    const float* __restrict__ x,
    const float* __restrict__ W_l, const float* __restrict__ b_l,
    const float* __restrict__ W_r, const float* __restrict__ b_r,
    unsigned short* __restrict__ xl_t, unsigned short* __restrict__ xr_t)
{
    __shared__ float xs[8][64];
    __shared__ unsigned short tl[8][256], tr[8][256];
    const int n0 = blockIdx.x * 8;
    const int t = threadIdx.x;
    for (int i = t; i < 8 * 64; i += 256) xs[i >> 6][i & 63] = x[n0 * 64 + i];
    __syncthreads();

    float accl[8], accr[8];
    const float bl = b_l[t], br = b_r[t];
#pragma unroll
    for (int n = 0; n < 8; n++) { accl[n] = bl; accr[n] = br; }
    for (int k = 0; k < 64; k++) {
        const float wl = W_l[k * 256 + t];
        const float wr = W_r[k * 256 + t];
#pragma unroll
        for (int n = 0; n < 8; n++) {
            accl[n] = fmaf(xs[n][k], wl, accl[n]);
            accr[n] = fmaf(xs[n][k], wr, accr[n]);
        }
    }
    const int pos = (t & 15) * 16 + (t >> 4);   // transposed-tiled position of channel t
#pragma unroll
    for (int n = 0; n < 8; n++) {
        tl[n][pos] = f2bf(accl[n]);
        tr[n][pos] = f2bf(accr[n]);
    }
    __syncthreads();
    // coalesced write-out: thread t -> node t>>5, 8 ushorts at (t&31)*8
    const int n = t >> 5, q = t & 31;
    ushort4 v0 = *(const ushort4*)&tl[n][q * 8];
    ushort4 v1 = *(const ushort4*)&tl[n][q * 8 + 4];
    ushort4 w0 = *(const ushort4*)&tr[n][q * 8];
    ushort4 w1 = *(const ushort4*)&tr[n][q * 8 + 4];
    *(ushort4*)(xl_t + (size_t)(n0 + n) * 256 + q * 8)     = v0;
    *(ushort4*)(xl_t + (size_t)(n0 + n) * 256 + q * 8 + 4) = v1;
    *(ushort4*)(xr_t + (size_t)(n0 + n) * 256 + q * 8)     = w0;
    *(ushort4*)(xr_t + (size_t)(n0 + n) * 256 + q * 8 + 4) = w1;
}

// ---------------- K1b: prep W_e B-frags (bf16) + att_t ----------------------
__global__ __launch_bounds__(256) void k_prep(
    const float* __restrict__ W_e, const float* __restrict__ att,
    unsigned short* __restrict__ wfrag, unsigned short* __restrict__ att_t)
{
    const int t = threadIdx.x;
#pragma unroll
    for (int s = 0; s < 4; s++) {
        const int slot = t * 4 + s;            // 1024 slots = 16 nt x 64 lanes
        const int nt = slot >> 6, ls = slot & 63;
        const int col = nt * 16 + (ls & 15);
        const int kb = (ls >> 4) * 8;
#pragma unroll
        for (int j = 0; j < 8; j++)
            wfrag[slot * 8 + j] = f2bf(W_e[(kb + j) * 256 + col]);
    }
    // att_t[pos] = att_flat[c], pos = (c&15)*16+(c>>4)  (16x16 transpose)
    att_t[t] = f2bf(att[(t & 15) * 16 + (t >> 4)]);
}

// ---------------- K2: histogram of dst ------------------------------------
__global__ __launch_bounds__(256) void k_hist(const int* __restrict__ ei, int* __restrict__ count)
{
    const int e = blockIdx.x * 256 + threadIdx.x;
    if (e < N_EDGES) atomicAdd(&count[ei[N_EDGES + e]], 1);
}

// ---------------- K3: exclusive scan (single block) ------------------------
__global__ __launch_bounds__(1024) void k_scan(const int* __restrict__ count, int* __restrict__ off)
{
    __shared__ int wsum[16];
    __shared__ int s_carry;
    const int t = threadIdx.x, lane = t & 63, wv = t >> 6;
    if (t == 0) s_carry = 0;
    __syncthreads();
    for (int base = 0; base < N_NODES; base += 8192) {
        const int idx0 = base + t * 8;
        int v[8];
#pragma unroll
        for (int j = 0; j < 8; j++) { int i = idx0 + j; v[j] = (i < N_NODES) ? count[i] : 0; }
#pragma unroll
        for (int j = 1; j < 8; j++) v[j] += v[j - 1];
        const int tot = v[7];
        int sc = tot;
#pragma unroll
        for (int s = 1; s < 64; s <<= 1) { int o = __shfl_up(sc, s, 64); if (lane >= s) sc += o; }
        if (lane == 63) wsum[wv] = sc;
        __syncthreads();
        const int carry = s_carry;
        int woff = 0;
        for (int u = 0; u < wv; u++) woff += wsum[u];
        const int ebase = carry + woff + (sc - tot);
#pragma unroll
        for (int j = 0; j < 8; j++) {
            int i = idx0 + j;
            if (i < N_NODES) off[i] = ebase + (j ? v[j - 1] : 0);
        }
        __syncthreads();
        if (t == 0) { int tt = 0; for (int u = 0; u < 16; u++) tt += wsum[u]; s_carry = carry + tt; }
        __syncthreads();
    }
    if (threadIdx.x == 0) off[N_NODES] = s_carry;
}

// ---------------- K4: scatter src + PERMUTED bf16 edge_attr into CSR -------
__global__ __launch_bounds__(256) void k_scatter(
    const int* __restrict__ ei, const int* __restrict__ off, int* __restrict__ cursor,
    const float* __restrict__ edge_attr,
    int* __restrict__ csr_src, unsigned short* __restrict__ ea_csr)
{
    const int e = blockIdx.x * 256 + threadIdx.x;
    if (e < N_EDGES) {
        const int s = ei[e];
        const int d = ei[N_EDGES + e];
        const int pos = off[d] + atomicAdd(&cursor[d], 1);
        csr_src[pos] = s;
        const float4* src4 = (const float4*)(edge_attr + (size_t)e * 32);
        ushort4* dst4 = (ushort4*)(ea_csr + (size_t)pos * 32);
#pragma unroll
        for (int i = 0; i < 8; i++) {
            const float4 v = src4[i];
            ushort4 u;
            u.x = f2bf(v.x); u.y = f2bf(v.y); u.z = f2bf(v.z); u.w = f2bf(v.w);
            dst4[i] = u;
        }
    }
}

// ---------------- K5: FUSED all-register D-layout edge pipeline ------------
// 4 waves/block, wave = one node. Lane (arow=l&15, koct=l>>4) owns, for its
// 4 edges (D rows koct*4+r), channels {nt*16+arow}.
// Half-split xl consumption: heads 0-1 use xl bytes [0,16) of the lane's
// 32B slice, heads 2-3 use [16,32) (same 64B line -> L1 hit). This halves
// the xl register footprint (32->16 VGPR) to fit the 128-VGPR / 4-wave cap.
__global__ __launch_bounds__(256, 4) void k_fused(
    const int* __restrict__ off, const int* __restrict__ csr_src,
    const unsigned short* __restrict__ ea_csr,
    const unsigned short* __restrict__ wfrag, const unsigned short* __restrict__ att_t,
    const unsigned short* __restrict__ xl_t, const unsigned short* __restrict__ xr_t,
    const float* __restrict__ x, const float* __restrict__ bias_gat,
    const float* __restrict__ W1, const float* __restrict__ b1,
    const float* __restrict__ gamma, const float* __restrict__ beta,
    const float* __restrict__ W2, const float* __restrict__ b2,
    float* __restrict__ out)
{
    __shared__ unsigned short bfrag_s[16][64][8];   // 16 KB W_e B-frags
    __shared__ float zs[4][256];
    __shared__ float xs[4][64];
    __shared__ float part[4][4][64];
    __shared__ float redS[4][4], redQ[4][4];

    const int n0 = blockIdx.x * 4;
    const int t = threadIdx.x;
    const int lane = t & 63, wv = t >> 6;
    const int node = n0 + wv;
    const int arow = lane & 15, koct = lane >> 4;

    for (int i = t; i < 4 * 64; i += 256) xs[i >> 6][i & 63] = x[n0 * 64 + i];
    for (int i = t; i < 1024; i += 256)
        *(u16x8*)&bfrag_s[i >> 6][i & 63][0] = *(const u16x8*)(wfrag + i * 8);
    __syncthreads();

    const u16x8 attL = *(const u16x8*)(att_t + arow * 16);
    const u16x8 attH = *(const u16x8*)(att_t + arow * 16 + 8);
    const u16x8 xrL  = *(const u16x8*)(xr_t + (size_t)node * 256 + arow * 16);
    const u16x8 xrH  = *(const u16x8*)(xr_t + (size_t)node * 256 + arow * 16 + 8);

    const int mylo = off[node], myhi = off[node + 1];
    float g[16];
#pragma unroll
    for (int i = 0; i < 16; i++) g[i] = 0.f;
    float dsum[4] = {0.f, 0.f, 0.f, 0.f};

    for (int p0 = mylo; p0 < myhi; p0 += 16) {
        const int pa = min(p0 + arow, myhi - 1);
        const int sv = csr_src[pa];
        const bf16x8 af = *(const bf16x8*)(ea_csr + (size_t)pa * 32 + koct * 8);
        int src[4];
#pragma unroll
        for (int r = 0; r < 4; r++) src[r] = __shfl(sv, koct * 4 + r, 64);

#pragma unroll
        for (int half = 0; half < 2; half++) {
            u16x8 xh[4];
#pragma unroll
            for (int r = 0; r < 4; r++)
                xh[r] = *(const u16x8*)(xl_t + (size_t)src[r] * 256 + arow * 16 + half * 8);
            const u16x8 att8 = half ? attH : attL;
            const u16x8 xr8  = half ? xrH  : xrL;
#pragma unroll
            for (int hh = 0; hh < 2; hh++) {
                const int h = half * 2 + hh;
                float s4[4] = {0.f, 0.f, 0.f, 0.f};
#pragma unroll
                for (int q = 0; q < 4; q++) {
                    const int nt = h * 4 + q;
                    const int ntl = hh * 4 + q;   // local 0..7 within this half
                    const bf16x8 bfr = *(const bf16x8*)&bfrag_s[nt][lane][0];
                    f32x4 dacc = {0.f, 0.f, 0.f, 0.f};
                    dacc = __builtin_amdgcn_mfma_f32_16x16x32_bf16(af, bfr, dacc, 0, 0, 0);
                    const float xrv = bf2f((unsigned short)xr8[ntl]);
                    const float atv = bf2f((unsigned short)att8[ntl]);
#pragma unroll
                    for (int r = 0; r < 4; r++) {
                        const float xv = bf2f((unsigned short)xh[r][ntl]);
                        const float mm = dacc[r] + xv + xrv;
                        const float lk = fmaf(NEG_SLOPE, fminf(mm, 0.f), fmaxf(mm, 0.f));
                        s4[r] = fmaf(atv, lk, s4[r]);
                    }
                }
#pragma unroll
                for (int r = 0; r < 4; r++) {
                    float v = s4[r];
                    v += __shfl_xor(v, 1, 64);
                    v += __shfl_xor(v, 2, 64);
                    v += __shfl_xor(v, 4, 64);
                    v += __shfl_xor(v, 8, 64);
                    s4[r] = v;
                }
                float w4[4];
#pragma unroll
                for (int r = 0; r < 4; r++)
                    w4[r] = (p0 + koct * 4 + r < myhi) ? __expf(fminf(s4[r], 60.f)) : 0.f;
                dsum[h] += (w4[0] + w4[1]) + (w4[2] + w4[3]);
#pragma unroll
                for (int q = 0; q < 4; q++) {
                    const int nt = h * 4 + q;
                    const int ntl = hh * 4 + q;
                    float acc = g[nt];
#pragma unroll
                    for (int r = 0; r < 4; r++) {
                        const float xv = bf2f((unsigned short)xh[r][ntl]);
                        acc = fmaf(w4[r], xv, acc);
                    }
                    g[nt] = acc;
                }
            }
        }
    }
    // cross-koct reduction (4 partial groups -> full sums)
#pragma unroll
    for (int i = 0; i < 16; i++) {
        float v = g[i];
        v += __shfl_xor(v, 16, 64);
        v += __shfl_xor(v, 32, 64);
        g[i] = v;
    }
#pragma unroll
    for (int h = 0; h < 4; h++) {
        float v = dsum[h];
        v += __shfl_xor(v, 16, 64);
        v += __shfl_xor(v, 32, 64);
        dsum[h] = v;
    }
    float inv[4];
#pragma unroll
    for (int h = 0; h < 4; h++) inv[h] = 1.f / (dsum[h] + 1e-16f);
#pragma unroll
    for (int nt = 0; nt < 16; nt++) g[nt] *= inv[nt >> 2];
    if (koct == 0) {
#pragma unroll
        for (int nt = 0; nt < 16; nt++) zs[wv][nt * 16 + arow] = g[nt];
    }
    __syncthreads();

    // xl1 = tanh(x@W1+b1), channel t, 4 nodes
    float a1[4];
    const float b1v = b1[t];
#pragma unroll
    for (int n = 0; n < 4; n++) a1[n] = b1v;
    for (int k = 0; k < 64; k++) {
        const float w1v = W1[k * 256 + t];
#pragma unroll
        for (int n = 0; n < 4; n++) a1[n] = fmaf(xs[n][k], w1v, a1[n]);
    }

    const float bg = bias_gat[t];
    float z[4];
#pragma unroll
    for (int n = 0; n < 4; n++) z[n] = fast_tanh(a1[n]) + zs[n][t] + bg;

    // LayerNorm over 256 channels per node
    const float gm = gamma[t], bt = beta[t];
#pragma unroll
    for (int n = 0; n < 4; n++) {
        float s = z[n], q = z[n] * z[n];
#pragma unroll
        for (int m = 1; m < 64; m <<= 1) { s += __shfl_xor(s, m, 64); q += __shfl_xor(q, m, 64); }
        if (lane == 0) { redS[n][wv] = s; redQ[n][wv] = q; }
    }
    __syncthreads();
#pragma unroll
    for (int n = 0; n < 4; n++) {
        const float s = redS[n][0] + redS[n][1] + redS[n][2] + redS[n][3];
        const float q = redQ[n][0] + redQ[n][1] + redQ[n][2] + redQ[n][3];
        const float mu = s * (1.f / 256.f);
        const float var = q * (1.f / 256.f) - mu * mu;
        const float ivn = rsqrtf(var + LN_EPS);
        zs[n][t] = (z[n] - mu) * ivn * gm + bt;
    }
    __syncthreads();

    // out = tanh(z@W2 + b2): thread t -> output col j=t&63, K-chunk q=t>>6
    const int j = t & 63, q = t >> 6;
    float p[4] = {0.f, 0.f, 0.f, 0.f};
    for (int c0 = 0; c0 < 64; c0++) {
        const int c = q * 64 + c0;
        const float w2v = W2[c * 64 + j];
#pragma unroll
        for (int n = 0; n < 4; n++) p[n] = fmaf(zs[n][c], w2v, p[n]);
    }
#pragma unroll
    for (int n = 0; n < 4; n++) part[n][q][j] = p[n];
    __syncthreads();
    {
        const int n = t >> 6, jj = t & 63;
        const float s = part[n][0][jj] + part[n][1][jj] + part[n][2][jj] + part[n][3][jj];
        out[(n0 + n) * 64 + jj] = fast_tanh(s + b2[jj]);
    }
}

// ---------------- launcher --------------------------------------------------
extern "C" void kernel_launch(void* const* d_in, const int* in_sizes, int n_in,
                              void* d_out, int out_size, void* d_ws, size_t ws_size,
                              hipStream_t stream)
{
    const float* x         = (const float*)d_in[0];
    const int*   ei        = (const int*)d_in[1];
    const float* edge_attr = (const float*)d_in[2];
    const float* W_l       = (const float*)d_in[3];
    const float* b_l       = (const float*)d_in[4];
    const float* W_r       = (const float*)d_in[5];
    const float* b_r       = (const float*)d_in[6];
    const float* W_e       = (const float*)d_in[7];
    const float* att       = (const float*)d_in[8];
    const float* bias_gat  = (const float*)d_in[9];
    const float* W1        = (const float*)d_in[10];
    const float* b1        = (const float*)d_in[11];
    const float* gamma     = (const float*)d_in[12];
    const float* beta      = (const float*)d_in[13];
    const float* W2        = (const float*)d_in[14];
    const float* b2        = (const float*)d_in[15];
    float* out = (float*)d_out;

    char* ws = (char*)d_ws;
    unsigned short* xl_t   = (unsigned short*)ws;  ws += (size_t)N_NODES * HC * 2;   // 25.6 MB
    unsigned short* xr_t   = (unsigned short*)ws;  ws += (size_t)N_NODES * HC * 2;   // 25.6 MB
    unsigned short* ea_csr = (unsigned short*)ws;  ws += (size_t)N_EDGES * 32 * 2;   // 51.2 MB
    int* csr_src           = (int*)ws;             ws += (size_t)N_EDGES * 4;
    int* count             = (int*)ws;             ws += (size_t)N_NODES * 4;
    int* cursor            = (int*)ws;             ws += (size_t)N_NODES * 4;
    int* off               = (int*)ws;             ws += (size_t)(N_NODES + 1) * 4;
    unsigned short* wfrag  = (unsigned short*)ws;  ws += 16 * 64 * 8 * 2;            // 16 KB
    unsigned short* att_t  = (unsigned short*)ws;  ws += 256 * 2;

    // zero count + cursor (contiguous)
    hipMemsetAsync(count, 0, 2 * (size_t)N_NODES * sizeof(int), stream);

    k_node_transform<<<N_NODES / 8, 256, 0, stream>>>(x, W_l, b_l, W_r, b_r, xl_t, xr_t);
    k_prep<<<1, 256, 0, stream>>>(W_e, att, wfrag, att_t);
    k_hist<<<(N_EDGES + 255) / 256, 256, 0, stream>>>(ei, count);
    k_scan<<<1, 1024, 0, stream>>>(count, off);
    k_scatter<<<(N_EDGES + 255) / 256, 256, 0, stream>>>(ei, off, cursor, edge_attr,
                                                         csr_src, ea_csr);
    k_fused<<<N_NODES / 4, 256, 0, stream>>>(off, csr_src, ea_csr, wfrag, att_t,
                                             xl_t, xr_t, x, bias_gat,
                                             W1, b1, gamma, beta, W2, b2, out);
}

// Round 14
// 863.645 us; speedup vs baseline: 2.4254x; 2.4254x over previous
//
#include <hip/hip_runtime.h>
#include <math.h>

#define N_NODES 50000
#define N_EDGES 800000
#define HID 64
#define HEADS 4
#define HC 256
#define NEG_SLOPE 0.2f
#define LN_EPS 1e-5f

typedef __attribute__((ext_vector_type(8))) short bf16x8;
typedef __attribute__((ext_vector_type(8))) unsigned short u16x8;
typedef __attribute__((ext_vector_type(4))) float f32x4;

__device__ __forceinline__ float bf2f(unsigned short u) {
    return __uint_as_float(((unsigned int)u) << 16);
}
__device__ __forceinline__ unsigned short f2bf(float f) {
    unsigned int u = __float_as_uint(f);
    u = (u + 0x7fffu + ((u >> 16) & 1u)) >> 16;   // RNE
    return (unsigned short)u;
}
__device__ __forceinline__ float fast_tanh(float v) {
    const float c = fminf(fmaxf(v, -15.f), 15.f);
    const float e = __expf(2.f * c);
    return 1.f - 2.f / (e + 1.f);
}

// ---------------- K1: node transform -> TRANSPOSED-TILED bf16 xl_t / xr_t --
// xl_t[node][pos], pos = (c&15)*16 + (c>>4) for channel c. Lane(arow) then
// reads channels {nt*16+arow : nt=0..15} as 16 contiguous ushorts.
__global__ __launch_bounds__(256) void k_node_transform(
    const float* __restrict__ x,
    const float* __restrict__ W_l, const float* __restrict__ b_l,
    const float* __restrict__ W_r, const float* __restrict__ b_r,
    unsigned short* __restrict__ xl_t, unsigned short* __restrict__ xr_t)
{
    __shared__ float xs[8][64];
    __shared__ unsigned short tl[8][256], tr[8][256];
    const int n0 = blockIdx.x * 8;
    const int t = threadIdx.x;
    for (int i = t; i < 8 * 64; i += 256) xs[i >> 6][i & 63] = x[n0 * 64 + i];
    __syncthreads();

    float accl[8], accr[8];
    const float bl = b_l[t], br = b_r[t];
#pragma unroll
    for (int n = 0; n < 8; n++) { accl[n] = bl; accr[n] = br; }
    for (int k = 0; k < 64; k++) {
        const float wl = W_l[k * 256 + t];
        const float wr = W_r[k * 256 + t];
#pragma unroll
        for (int n = 0; n < 8; n++) {
            accl[n] = fmaf(xs[n][k], wl, accl[n]);
            accr[n] = fmaf(xs[n][k], wr, accr[n]);
        }
    }
    const int pos = (t & 15) * 16 + (t >> 4);   // transposed-tiled position of channel t
#pragma unroll
    for (int n = 0; n < 8; n++) {
        tl[n][pos] = f2bf(accl[n]);
        tr[n][pos] = f2bf(accr[n]);
    }
    __syncthreads();
    // coalesced write-out: thread t -> node t>>5, 8 ushorts at (t&31)*8
    const int n = t >> 5, q = t & 31;
    ushort4 v0 = *(const ushort4*)&tl[n][q * 8];
    ushort4 v1 = *(const ushort4*)&tl[n][q * 8 + 4];
    ushort4 w0 = *(const ushort4*)&tr[n][q * 8];
    ushort4 w1 = *(const ushort4*)&tr[n][q * 8 + 4];
    *(ushort4*)(xl_t + (size_t)(n0 + n) * 256 + q * 8)     = v0;
    *(ushort4*)(xl_t + (size_t)(n0 + n) * 256 + q * 8 + 4) = v1;
    *(ushort4*)(xr_t + (size_t)(n0 + n) * 256 + q * 8)     = w0;
    *(ushort4*)(xr_t + (size_t)(n0 + n) * 256 + q * 8 + 4) = w1;
}

// ---------------- K1b: prep W_e B-frags (bf16) + att_t ----------------------
__global__ __launch_bounds__(256) void k_prep(
    const float* __restrict__ W_e, const float* __restrict__ att,
    unsigned short* __restrict__ wfrag, unsigned short* __restrict__ att_t)
{
    const int t = threadIdx.x;
#pragma unroll
    for (int s = 0; s < 4; s++) {
        const int slot = t * 4 + s;            // 1024 slots = 16 nt x 64 lanes
        const int nt = slot >> 6, ls = slot & 63;
        const int col = nt * 16 + (ls & 15);
        const int kb = (ls >> 4) * 8;
#pragma unroll
        for (int j = 0; j < 8; j++)
            wfrag[slot * 8 + j] = f2bf(W_e[(kb + j) * 256 + col]);
    }
    // att_t[pos] = att_flat[c], pos = (c&15)*16+(c>>4)  (16x16 transpose)
    att_t[t] = f2bf(att[(t & 15) * 16 + (t >> 4)]);
}

// ---------------- K2: histogram of dst ------------------------------------
__global__ __launch_bounds__(256) void k_hist(const int* __restrict__ ei, int* __restrict__ count)
{
    const int e = blockIdx.x * 256 + threadIdx.x;
    if (e < N_EDGES) atomicAdd(&count[ei[N_EDGES + e]], 1);
}

// ---------------- K3: exclusive scan (single block) ------------------------
__global__ __launch_bounds__(1024) void k_scan(const int* __restrict__ count, int* __restrict__ off)
{
    __shared__ int wsum[16];
    __shared__ int s_carry;
    const int t = threadIdx.x, lane = t & 63, wv = t >> 6;
    if (t == 0) s_carry = 0;
    __syncthreads();
    for (int base = 0; base < N_NODES; base += 8192) {
        const int idx0 = base + t * 8;
        int v[8];
#pragma unroll
        for (int j = 0; j < 8; j++) { int i = idx0 + j; v[j] = (i < N_NODES) ? count[i] : 0; }
#pragma unroll
        for (int j = 1; j < 8; j++) v[j] += v[j - 1];
        const int tot = v[7];
        int sc = tot;
#pragma unroll
        for (int s = 1; s < 64; s <<= 1) { int o = __shfl_up(sc, s, 64); if (lane >= s) sc += o; }
        if (lane == 63) wsum[wv] = sc;
        __syncthreads();
        const int carry = s_carry;
        int woff = 0;
        for (int u = 0; u < wv; u++) woff += wsum[u];
        const int ebase = carry + woff + (sc - tot);
#pragma unroll
        for (int j = 0; j < 8; j++) {
            int i = idx0 + j;
            if (i < N_NODES) off[i] = ebase + (j ? v[j - 1] : 0);
        }
        __syncthreads();
        if (t == 0) { int tt = 0; for (int u = 0; u < 16; u++) tt += wsum[u]; s_carry = carry + tt; }
        __syncthreads();
    }
    if (threadIdx.x == 0) off[N_NODES] = s_carry;
}

// ---------------- K4: scatter src + PERMUTED bf16 edge_attr into CSR -------
__global__ __launch_bounds__(256) void k_scatter(
    const int* __restrict__ ei, const int* __restrict__ off, int* __restrict__ cursor,
    const float* __restrict__ edge_attr,
    int* __restrict__ csr_src, unsigned short* __restrict__ ea_csr)
{
    const int e = blockIdx.x * 256 + threadIdx.x;
    if (e < N_EDGES) {
        const int s = ei[e];
        const int d = ei[N_EDGES + e];
        const int pos = off[d] + atomicAdd(&cursor[d], 1);
        csr_src[pos] = s;
        const float4* src4 = (const float4*)(edge_attr + (size_t)e * 32);
        ushort4* dst4 = (ushort4*)(ea_csr + (size_t)pos * 32);
#pragma unroll
        for (int i = 0; i < 8; i++) {
            const float4 v = src4[i];
            ushort4 u;
            u.x = f2bf(v.x); u.y = f2bf(v.y); u.z = f2bf(v.z); u.w = f2bf(v.w);
            dst4[i] = u;
        }
    }
}

// ---------------- K5: FUSED all-register D-layout edge pipeline ------------
// 4 waves/block, wave = one node. Lane (arow=l&15, koct=l>>4) owns, for its
// 4 edges (D rows koct*4+r), channels {nt*16+arow}.
// Half-split xl consumption: heads 0-1 use xl bytes [0,16) of the lane's
// 32B slice, heads 2-3 use [16,32) (same 64B line -> L1 hit). Halves the xl
// register footprint; NO launch-bounds cap (caps force spills - r7/r12).
__global__ __launch_bounds__(256) void k_fused(
    const int* __restrict__ off, const int* __restrict__ csr_src,
    const unsigned short* __restrict__ ea_csr,
    const unsigned short* __restrict__ wfrag, const unsigned short* __restrict__ att_t,
    const unsigned short* __restrict__ xl_t, const unsigned short* __restrict__ xr_t,
    const float* __restrict__ x, const float* __restrict__ bias_gat,
    const float* __restrict__ W1, const float* __restrict__ b1,
    const float* __restrict__ gamma, const float* __restrict__ beta,
    const float* __restrict__ W2, const float* __restrict__ b2,
    float* __restrict__ out)
{
    __shared__ unsigned short bfrag_s[16][64][8];   // 16 KB W_e B-frags
    __shared__ float zs[4][256];
    __shared__ float xs[4][64];
    __shared__ float part[4][4][64];
    __shared__ float redS[4][4], redQ[4][4];

    const int n0 = blockIdx.x * 4;
    const int t = threadIdx.x;
    const int lane = t & 63, wv = t >> 6;
    const int node = n0 + wv;
    const int arow = lane & 15, koct = lane >> 4;

    for (int i = t; i < 4 * 64; i += 256) xs[i >> 6][i & 63] = x[n0 * 64 + i];
    for (int i = t; i < 1024; i += 256)
        *(u16x8*)&bfrag_s[i >> 6][i & 63][0] = *(const u16x8*)(wfrag + i * 8);
    __syncthreads();

    const u16x8 attL = *(const u16x8*)(att_t + arow * 16);
    const u16x8 attH = *(const u16x8*)(att_t + arow * 16 + 8);
    const u16x8 xrL  = *(const u16x8*)(xr_t + (size_t)node * 256 + arow * 16);
    const u16x8 xrH  = *(const u16x8*)(xr_t + (size_t)node * 256 + arow * 16 + 8);

    const int mylo = off[node], myhi = off[node + 1];
    float g[16];
#pragma unroll
    for (int i = 0; i < 16; i++) g[i] = 0.f;
    float dsum[4] = {0.f, 0.f, 0.f, 0.f};

    for (int p0 = mylo; p0 < myhi; p0 += 16) {
        const int pa = min(p0 + arow, myhi - 1);
        const int sv = csr_src[pa];
        const bf16x8 af = *(const bf16x8*)(ea_csr + (size_t)pa * 32 + koct * 8);
        int src[4];
#pragma unroll
        for (int r = 0; r < 4; r++) src[r] = __shfl(sv, koct * 4 + r, 64);

#pragma unroll
        for (int half = 0; half < 2; half++) {
            u16x8 xh[4];
#pragma unroll
            for (int r = 0; r < 4; r++)
                xh[r] = *(const u16x8*)(xl_t + (size_t)src[r] * 256 + arow * 16 + half * 8);
            const u16x8 att8 = half ? attH : attL;
            const u16x8 xr8  = half ? xrH  : xrL;
#pragma unroll
            for (int hh = 0; hh < 2; hh++) {
                const int h = half * 2 + hh;
                float s4[4] = {0.f, 0.f, 0.f, 0.f};
#pragma unroll
                for (int q = 0; q < 4; q++) {
                    const int nt = h * 4 + q;
                    const int ntl = hh * 4 + q;   // local 0..7 within this half
                    const bf16x8 bfr = *(const bf16x8*)&bfrag_s[nt][lane][0];
                    f32x4 dacc = {0.f, 0.f, 0.f, 0.f};
                    dacc = __builtin_amdgcn_mfma_f32_16x16x32_bf16(af, bfr, dacc, 0, 0, 0);
                    const float xrv = bf2f((unsigned short)xr8[ntl]);
                    const float atv = bf2f((unsigned short)att8[ntl]);
#pragma unroll
                    for (int r = 0; r < 4; r++) {
                        const float xv = bf2f((unsigned short)xh[r][ntl]);
                        const float mm = dacc[r] + xv + xrv;
                        const float lk = fmaf(NEG_SLOPE, fminf(mm, 0.f), fmaxf(mm, 0.f));
                        s4[r] = fmaf(atv, lk, s4[r]);
                    }
                }
#pragma unroll
                for (int r = 0; r < 4; r++) {
                    float v = s4[r];
                    v += __shfl_xor(v, 1, 64);
                    v += __shfl_xor(v, 2, 64);
                    v += __shfl_xor(v, 4, 64);
                    v += __shfl_xor(v, 8, 64);
                    s4[r] = v;
                }
                float w4[4];
#pragma unroll
                for (int r = 0; r < 4; r++)
                    w4[r] = (p0 + koct * 4 + r < myhi) ? __expf(fminf(s4[r], 60.f)) : 0.f;
                dsum[h] += (w4[0] + w4[1]) + (w4[2] + w4[3]);
#pragma unroll
                for (int q = 0; q < 4; q++) {
                    const int nt = h * 4 + q;
                    const int ntl = hh * 4 + q;
                    float acc = g[nt];
#pragma unroll
                    for (int r = 0; r < 4; r++) {
                        const float xv = bf2f((unsigned short)xh[r][ntl]);
                        acc = fmaf(w4[r], xv, acc);
                    }
                    g[nt] = acc;
                }
            }
        }
    }
    // cross-koct reduction (4 partial groups -> full sums)
#pragma unroll
    for (int i = 0; i < 16; i++) {
        float v = g[i];
        v += __shfl_xor(v, 16, 64);
        v += __shfl_xor(v, 32, 64);
        g[i] = v;
    }
#pragma unroll
    for (int h = 0; h < 4; h++) {
        float v = dsum[h];
        v += __shfl_xor(v, 16, 64);
        v += __shfl_xor(v, 32, 64);
        dsum[h] = v;
    }
    float inv[4];
#pragma unroll
    for (int h = 0; h < 4; h++) inv[h] = 1.f / (dsum[h] + 1e-16f);
#pragma unroll
    for (int nt = 0; nt < 16; nt++) g[nt] *= inv[nt >> 2];
    if (koct == 0) {
#pragma unroll
        for (int nt = 0; nt < 16; nt++) zs[wv][nt * 16 + arow] = g[nt];
    }
    __syncthreads();

    // xl1 = tanh(x@W1+b1), channel t, 4 nodes
    float a1[4];
    const float b1v = b1[t];
#pragma unroll
    for (int n = 0; n < 4; n++) a1[n] = b1v;
    for (int k = 0; k < 64; k++) {
        const float w1v = W1[k * 256 + t];
#pragma unroll
        for (int n = 0; n < 4; n++) a1[n] = fmaf(xs[n][k], w1v, a1[n]);
    }

    const float bg = bias_gat[t];
    float z[4];
#pragma unroll
    for (int n = 0; n < 4; n++) z[n] = fast_tanh(a1[n]) + zs[n][t] + bg;

    // LayerNorm over 256 channels per node
    const float gm = gamma[t], bt = beta[t];
#pragma unroll
    for (int n = 0; n < 4; n++) {
        float s = z[n], q = z[n] * z[n];
#pragma unroll
        for (int m = 1; m < 64; m <<= 1) { s += __shfl_xor(s, m, 64); q += __shfl_xor(q, m, 64); }
        if (lane == 0) { redS[n][wv] = s; redQ[n][wv] = q; }
    }
    __syncthreads();
#pragma unroll
    for (int n = 0; n < 4; n++) {
        const float s = redS[n][0] + redS[n][1] + redS[n][2] + redS[n][3];
        const float q = redQ[n][0] + redQ[n][1] + redQ[n][2] + redQ[n][3];
        const float mu = s * (1.f / 256.f);
        const float var = q * (1.f / 256.f) - mu * mu;
        const float ivn = rsqrtf(var + LN_EPS);
        zs[n][t] = (z[n] - mu) * ivn * gm + bt;
    }
    __syncthreads();

    // out = tanh(z@W2 + b2): thread t -> output col j=t&63, K-chunk q=t>>6
    const int j = t & 63, q = t >> 6;
    float p[4] = {0.f, 0.f, 0.f, 0.f};
    for (int c0 = 0; c0 < 64; c0++) {
        const int c = q * 64 + c0;
        const float w2v = W2[c * 64 + j];
#pragma unroll
        for (int n = 0; n < 4; n++) p[n] = fmaf(zs[n][c], w2v, p[n]);
    }
#pragma unroll
    for (int n = 0; n < 4; n++) part[n][q][j] = p[n];
    __syncthreads();
    {
        const int n = t >> 6, jj = t & 63;
        const float s = part[n][0][jj] + part[n][1][jj] + part[n][2][jj] + part[n][3][jj];
        out[(n0 + n) * 64 + jj] = fast_tanh(s + b2[jj]);
    }
}

// ---------------- launcher --------------------------------------------------
extern "C" void kernel_launch(void* const* d_in, const int* in_sizes, int n_in,
                              void* d_out, int out_size, void* d_ws, size_t ws_size,
                              hipStream_t stream)
{
    const float* x         = (const float*)d_in[0];
    const int*   ei        = (const int*)d_in[1];
    const float* edge_attr = (const float*)d_in[2];
    const float* W_l       = (const float*)d_in[3];
    const float* b_l       = (const float*)d_in[4];
    const float* W_r       = (const float*)d_in[5];
    const float* b_r       = (const float*)d_in[6];
    const float* W_e       = (const float*)d_in[7];
    const float* att       = (const float*)d_in[8];
    const float* bias_gat  = (const float*)d_in[9];
    const float* W1        = (const float*)d_in[10];
    const float* b1        = (const float*)d_in[11];
    const float* gamma     = (const float*)d_in[12];
    const float* beta      = (const float*)d_in[13];
    const float* W2        = (const float*)d_in[14];
    const float* b2        = (const float*)d_in[15];
    float* out = (float*)d_out;

    char* ws = (char*)d_ws;
    unsigned short* xl_t   = (unsigned short*)ws;  ws += (size_t)N_NODES * HC * 2;   // 25.6 MB
    unsigned short* xr_t   = (unsigned short*)ws;  ws += (size_t)N_NODES * HC * 2;   // 25.6 MB
    unsigned short* ea_csr = (unsigned short*)ws;  ws += (size_t)N_EDGES * 32 * 2;   // 51.2 MB
    int* csr_src           = (int*)ws;             ws += (size_t)N_EDGES * 4;
    int* count             = (int*)ws;             ws += (size_t)N_NODES * 4;
    int* cursor            = (int*)ws;             ws += (size_t)N_NODES * 4;
    int* off               = (int*)ws;             ws += (size_t)(N_NODES + 1) * 4;
    unsigned short* wfrag  = (unsigned short*)ws;  ws += 16 * 64 * 8 * 2;            // 16 KB
    unsigned short* att_t  = (unsigned short*)ws;  ws += 256 * 2;

    // zero count + cursor (contiguous)
    hipMemsetAsync(count, 0, 2 * (size_t)N_NODES * sizeof(int), stream);

    k_node_transform<<<N_NODES / 8, 256, 0, stream>>>(x, W_l, b_l, W_r, b_r, xl_t, xr_t);
    k_prep<<<1, 256, 0, stream>>>(W_e, att, wfrag, att_t);
    k_hist<<<(N_EDGES + 255) / 256, 256, 0, stream>>>(ei, count);
    k_scan<<<1, 1024, 0, stream>>>(count, off);
    k_scatter<<<(N_EDGES + 255) / 256, 256, 0, stream>>>(ei, off, cursor, edge_attr,
                                                         csr_src, ea_csr);
    k_fused<<<N_NODES / 4, 256, 0, stream>>>(off, csr_src, ea_csr, wfrag, att_t,
                                             xl_t, xr_t, x, bias_gat,
                                             W1, b1, gamma, beta, W2, b2, out);
}

// Round 15
// 682.170 us; speedup vs baseline: 3.0707x; 1.2660x over previous
//
#include <hip/hip_runtime.h>
#include <math.h>

#define N_NODES 50000
#define N_EDGES 800000
#define HID 64
#define HEADS 4
#define HC 256
#define NEG_SLOPE 0.2f
#define LN_EPS 1e-5f
#define EDGE_BLOCKS 2048   // persistent-wave grid for k_edgeagg (8192 waves)

typedef __attribute__((ext_vector_type(8))) short bf16x8;
typedef __attribute__((ext_vector_type(8))) unsigned short u16x8;
typedef __attribute__((ext_vector_type(4))) float f32x4;

__device__ __forceinline__ float bf2f(unsigned short u) {
    return __uint_as_float(((unsigned int)u) << 16);
}
__device__ __forceinline__ unsigned short f2bf(float f) {
    unsigned int u = __float_as_uint(f);
    u = (u + 0x7fffu + ((u >> 16) & 1u)) >> 16;   // RNE
    return (unsigned short)u;
}
__device__ __forceinline__ float fast_tanh(float v) {
    const float c = fminf(fmaxf(v, -15.f), 15.f);
    const float e = __expf(2.f * c);
    return 1.f - 2.f / (e + 1.f);
}

// ---------------- K1: node transform -> TRANSPOSED-TILED bf16 xl_t / xr_t --
// xl_t[node][pos], pos = (c&15)*16 + (c>>4) for channel c.
__global__ __launch_bounds__(256) void k_node_transform(
    const float* __restrict__ x,
    const float* __restrict__ W_l, const float* __restrict__ b_l,
    const float* __restrict__ W_r, const float* __restrict__ b_r,
    unsigned short* __restrict__ xl_t, unsigned short* __restrict__ xr_t)
{
    __shared__ float xs[8][64];
    __shared__ unsigned short tl[8][256], tr[8][256];
    const int n0 = blockIdx.x * 8;
    const int t = threadIdx.x;
    for (int i = t; i < 8 * 64; i += 256) xs[i >> 6][i & 63] = x[n0 * 64 + i];
    __syncthreads();

    float accl[8], accr[8];
    const float bl = b_l[t], br = b_r[t];
#pragma unroll
    for (int n = 0; n < 8; n++) { accl[n] = bl; accr[n] = br; }
    for (int k = 0; k < 64; k++) {
        const float wl = W_l[k * 256 + t];
        const float wr = W_r[k * 256 + t];
#pragma unroll
        for (int n = 0; n < 8; n++) {
            accl[n] = fmaf(xs[n][k], wl, accl[n]);
            accr[n] = fmaf(xs[n][k], wr, accr[n]);
        }
    }
    const int pos = (t & 15) * 16 + (t >> 4);
#pragma unroll
    for (int n = 0; n < 8; n++) {
        tl[n][pos] = f2bf(accl[n]);
        tr[n][pos] = f2bf(accr[n]);
    }
    __syncthreads();
    const int n = t >> 5, q = t & 31;
    ushort4 v0 = *(const ushort4*)&tl[n][q * 8];
    ushort4 v1 = *(const ushort4*)&tl[n][q * 8 + 4];
    ushort4 w0 = *(const ushort4*)&tr[n][q * 8];
    ushort4 w1 = *(const ushort4*)&tr[n][q * 8 + 4];
    *(ushort4*)(xl_t + (size_t)(n0 + n) * 256 + q * 8)     = v0;
    *(ushort4*)(xl_t + (size_t)(n0 + n) * 256 + q * 8 + 4) = v1;
    *(ushort4*)(xr_t + (size_t)(n0 + n) * 256 + q * 8)     = w0;
    *(ushort4*)(xr_t + (size_t)(n0 + n) * 256 + q * 8 + 4) = w1;
}

// ---------------- K1b: prep W_e B-frags (bf16) + att_t ----------------------
__global__ __launch_bounds__(256) void k_prep(
    const float* __restrict__ W_e, const float* __restrict__ att,
    unsigned short* __restrict__ wfrag, unsigned short* __restrict__ att_t)
{
    const int t = threadIdx.x;
#pragma unroll
    for (int s = 0; s < 4; s++) {
        const int slot = t * 4 + s;
        const int nt = slot >> 6, ls = slot & 63;
        const int col = nt * 16 + (ls & 15);
        const int kb = (ls >> 4) * 8;
#pragma unroll
        for (int j = 0; j < 8; j++)
            wfrag[slot * 8 + j] = f2bf(W_e[(kb + j) * 256 + col]);
    }
    att_t[t] = f2bf(att[(t & 15) * 16 + (t >> 4)]);
}

// ---------------- K2: histogram of dst ------------------------------------
__global__ __launch_bounds__(256) void k_hist(const int* __restrict__ ei, int* __restrict__ count)
{
    const int e = blockIdx.x * 256 + threadIdx.x;
    if (e < N_EDGES) atomicAdd(&count[ei[N_EDGES + e]], 1);
}

// ---------------- K3: exclusive scan (single block) ------------------------
__global__ __launch_bounds__(1024) void k_scan(const int* __restrict__ count, int* __restrict__ off)
{
    __shared__ int wsum[16];
    __shared__ int s_carry;
    const int t = threadIdx.x, lane = t & 63, wv = t >> 6;
    if (t == 0) s_carry = 0;
    __syncthreads();
    for (int base = 0; base < N_NODES; base += 8192) {
        const int idx0 = base + t * 8;
        int v[8];
#pragma unroll
        for (int j = 0; j < 8; j++) { int i = idx0 + j; v[j] = (i < N_NODES) ? count[i] : 0; }
#pragma unroll
        for (int j = 1; j < 8; j++) v[j] += v[j - 1];
        const int tot = v[7];
        int sc = tot;
#pragma unroll
        for (int s = 1; s < 64; s <<= 1) { int o = __shfl_up(sc, s, 64); if (lane >= s) sc += o; }
        if (lane == 63) wsum[wv] = sc;
        __syncthreads();
        const int carry = s_carry;
        int woff = 0;
        for (int u = 0; u < wv; u++) woff += wsum[u];
        const int ebase = carry + woff + (sc - tot);
#pragma unroll
        for (int j = 0; j < 8; j++) {
            int i = idx0 + j;
            if (i < N_NODES) off[i] = ebase + (j ? v[j - 1] : 0);
        }
        __syncthreads();
        if (t == 0) { int tt = 0; for (int u = 0; u < 16; u++) tt += wsum[u]; s_carry = carry + tt; }
        __syncthreads();
    }
    if (threadIdx.x == 0) off[N_NODES] = s_carry;
}

// ---------------- K4: scatter src + PERMUTED bf16 edge_attr into CSR -------
__global__ __launch_bounds__(256) void k_scatter(
    const int* __restrict__ ei, const int* __restrict__ off, int* __restrict__ cursor,
    const float* __restrict__ edge_attr,
    int* __restrict__ csr_src, unsigned short* __restrict__ ea_csr)
{
    const int e = blockIdx.x * 256 + threadIdx.x;
    if (e < N_EDGES) {
        const int s = ei[e];
        const int d = ei[N_EDGES + e];
        const int pos = off[d] + atomicAdd(&cursor[d], 1);
        csr_src[pos] = s;
        const float4* src4 = (const float4*)(edge_attr + (size_t)e * 32);
        ushort4* dst4 = (ushort4*)(ea_csr + (size_t)pos * 32);
#pragma unroll
        for (int i = 0; i < 8; i++) {
            const float4 v = src4[i];
            ushort4 u;
            u.x = f2bf(v.x); u.y = f2bf(v.y); u.z = f2bf(v.z); u.w = f2bf(v.w);
            dst4[i] = u;
        }
    }
}

// ---------------- K5: edge+aggregate, persistent waves, r10 inner loop -----
// Wave = one node at a time, grid-stride over nodes (6-7 nodes/wave).
// bfrag staged ONCE per block; no barriers afterwards. Writes normalized
// per-node g (256 ch) to zs_g (f32 or bf16 chosen by launcher via template).
template<bool F32>
__global__ __launch_bounds__(256) void k_edgeagg(
    const int* __restrict__ off, const int* __restrict__ csr_src,
    const unsigned short* __restrict__ ea_csr,
    const unsigned short* __restrict__ wfrag, const unsigned short* __restrict__ att_t,
    const unsigned short* __restrict__ xl_t, const unsigned short* __restrict__ xr_t,
    void* __restrict__ zs_g)
{
    __shared__ unsigned short bfrag_s[16][64][8];   // 16 KB, only LDS

    const int t = threadIdx.x;
    const int lane = t & 63, wv = t >> 6;
    const int arow = lane & 15, koct = lane >> 4;

    for (int i = t; i < 1024; i += 256)
        *(u16x8*)&bfrag_s[i >> 6][i & 63][0] = *(const u16x8*)(wfrag + i * 8);
    __syncthreads();

    const u16x8 attL = *(const u16x8*)(att_t + arow * 16);
    const u16x8 attH = *(const u16x8*)(att_t + arow * 16 + 8);

    const int wid = blockIdx.x * 4 + wv;
    for (int node = wid; node < N_NODES; node += EDGE_BLOCKS * 4) {
        const u16x8 xrL = *(const u16x8*)(xr_t + (size_t)node * 256 + arow * 16);
        const u16x8 xrH = *(const u16x8*)(xr_t + (size_t)node * 256 + arow * 16 + 8);
        const int mylo = off[node], myhi = off[node + 1];

        float g[16];
#pragma unroll
        for (int i = 0; i < 16; i++) g[i] = 0.f;
        float dsum[4] = {0.f, 0.f, 0.f, 0.f};

        for (int p0 = mylo; p0 < myhi; p0 += 16) {
            const int pa = min(p0 + arow, myhi - 1);
            const int sv = csr_src[pa];
            const bf16x8 af = *(const bf16x8*)(ea_csr + (size_t)pa * 32 + koct * 8);
            int src[4];
#pragma unroll
            for (int r = 0; r < 4; r++) src[r] = __shfl(sv, koct * 4 + r, 64);
            u16x8 xlo[4], xhi[4];
#pragma unroll
            for (int r = 0; r < 4; r++) {
                const unsigned short* bp = xl_t + (size_t)src[r] * 256 + arow * 16;
                xlo[r] = *(const u16x8*)bp;
                xhi[r] = *(const u16x8*)(bp + 8);
            }
            float s_[4][4];
#pragma unroll
            for (int r = 0; r < 4; r++)
#pragma unroll
                for (int h = 0; h < 4; h++) s_[r][h] = 0.f;

#pragma unroll
            for (int nt = 0; nt < 16; nt++) {
                const bf16x8 bfr = *(const bf16x8*)&bfrag_s[nt][lane][0];
                f32x4 dacc = {0.f, 0.f, 0.f, 0.f};
                dacc = __builtin_amdgcn_mfma_f32_16x16x32_bf16(af, bfr, dacc, 0, 0, 0);
                const float xrv = bf2f((unsigned short)(nt < 8 ? xrL[nt & 7] : xrH[nt & 7]));
                const float atv = bf2f((unsigned short)(nt < 8 ? attL[nt & 7] : attH[nt & 7]));
                const int h = nt >> 2;
#pragma unroll
                for (int r = 0; r < 4; r++) {
                    const float xv = bf2f((unsigned short)(nt < 8 ? xlo[r][nt & 7] : xhi[r][nt & 7]));
                    float mm = dacc[r] + xv + xrv;
                    mm = (mm > 0.f) ? mm : NEG_SLOPE * mm;
                    s_[r][h] = fmaf(atv, mm, s_[r][h]);
                }
            }
#pragma unroll
            for (int r = 0; r < 4; r++)
#pragma unroll
                for (int h = 0; h < 4; h++) {
                    float v = s_[r][h];
                    v += __shfl_xor(v, 1, 64);
                    v += __shfl_xor(v, 2, 64);
                    v += __shfl_xor(v, 4, 64);
                    v += __shfl_xor(v, 8, 64);
                    s_[r][h] = v;
                }
#pragma unroll
            for (int h = 0; h < 4; h++) {
                float w4[4];
#pragma unroll
                for (int r = 0; r < 4; r++) {
                    const bool ok = (p0 + koct * 4 + r) < myhi;
                    w4[r] = ok ? __expf(fminf(s_[r][h], 60.f)) : 0.f;
                }
                dsum[h] += (w4[0] + w4[1]) + (w4[2] + w4[3]);
#pragma unroll
                for (int q = 0; q < 4; q++) {
                    const int nt = h * 4 + q;
                    float acc = g[nt];
#pragma unroll
                    for (int r = 0; r < 4; r++) {
                        const float xv = bf2f((unsigned short)(nt < 8 ? xlo[r][nt & 7] : xhi[r][nt & 7]));
                        acc = fmaf(w4[r], xv, acc);
                    }
                    g[nt] = acc;
                }
            }
        }
        // cross-koct reduction
#pragma unroll
        for (int i = 0; i < 16; i++) {
            float v = g[i];
            v += __shfl_xor(v, 16, 64);
            v += __shfl_xor(v, 32, 64);
            g[i] = v;
        }
#pragma unroll
        for (int h = 0; h < 4; h++) {
            float v = dsum[h];
            v += __shfl_xor(v, 16, 64);
            v += __shfl_xor(v, 32, 64);
            dsum[h] = v;
        }
        float inv[4];
#pragma unroll
        for (int h = 0; h < 4; h++) inv[h] = 1.f / (dsum[h] + 1e-16f);
        // write normalized g: lane (arow,koct) owns channels (koct*4+q)*16+arow
#pragma unroll
        for (int q = 0; q < 4; q++) {
            const int nt = koct * 4 + q;
            const float v = g[nt] * inv[nt >> 2];
            if (F32)
                ((float*)zs_g)[(size_t)node * 256 + nt * 16 + arow] = v;
            else
                ((unsigned short*)zs_g)[(size_t)node * 256 + nt * 16 + arow] = f2bf(v);
        }
    }
}

// ---------------- K6: epilogue (MLP + LN + out-GEMM), 16 nodes/block -------
template<bool F32>
__global__ __launch_bounds__(256) void k_post(
    const void* __restrict__ zs_g, const float* __restrict__ x,
    const float* __restrict__ bias_gat,
    const float* __restrict__ W1, const float* __restrict__ b1,
    const float* __restrict__ gamma, const float* __restrict__ beta,
    const float* __restrict__ W2, const float* __restrict__ b2,
    float* __restrict__ out)
{
    __shared__ float xs[16][64];
    __shared__ float zsh[16][256];
    __shared__ float part[16][4][64];
    __shared__ float redS[16][4], redQ[16][4];

    const int n0 = blockIdx.x * 16;
    const int t = threadIdx.x, lane = t & 63, wv = t >> 6;

    for (int i = t; i < 16 * 64; i += 256) xs[i >> 6][i & 63] = x[n0 * 64 + i];
    __syncthreads();

    float a1[16];
    const float b1v = b1[t];
#pragma unroll
    for (int n = 0; n < 16; n++) a1[n] = b1v;
    for (int k = 0; k < 64; k++) {
        const float w1v = W1[k * 256 + t];
#pragma unroll
        for (int n = 0; n < 16; n++) a1[n] = fmaf(xs[n][k], w1v, a1[n]);
    }

    const float bg = bias_gat[t];
    float z[16];
#pragma unroll
    for (int n = 0; n < 16; n++) {
        const float gv = F32 ? ((const float*)zs_g)[(size_t)(n0 + n) * 256 + t]
                             : bf2f(((const unsigned short*)zs_g)[(size_t)(n0 + n) * 256 + t]);
        z[n] = fast_tanh(a1[n]) + gv + bg;
    }

    const float gm = gamma[t], bt = beta[t];
#pragma unroll
    for (int n = 0; n < 16; n++) {
        float s = z[n], q = z[n] * z[n];
#pragma unroll
        for (int m = 1; m < 64; m <<= 1) { s += __shfl_xor(s, m, 64); q += __shfl_xor(q, m, 64); }
        if (lane == 0) { redS[n][wv] = s; redQ[n][wv] = q; }
    }
    __syncthreads();
#pragma unroll
    for (int n = 0; n < 16; n++) {
        const float s = redS[n][0] + redS[n][1] + redS[n][2] + redS[n][3];
        const float q = redQ[n][0] + redQ[n][1] + redQ[n][2] + redQ[n][3];
        const float mu = s * (1.f / 256.f);
        const float var = q * (1.f / 256.f) - mu * mu;
        const float ivn = rsqrtf(var + LN_EPS);
        zsh[n][t] = (z[n] - mu) * ivn * gm + bt;
    }
    __syncthreads();

    const int j = t & 63, qq = t >> 6;
    float p[16];
#pragma unroll
    for (int n = 0; n < 16; n++) p[n] = 0.f;
    for (int c0 = 0; c0 < 64; c0++) {
        const int c = qq * 64 + c0;
        const float w2v = W2[c * 64 + j];
#pragma unroll
        for (int n = 0; n < 16; n++) p[n] = fmaf(zsh[n][c], w2v, p[n]);
    }
#pragma unroll
    for (int n = 0; n < 16; n++) part[n][qq][j] = p[n];
    __syncthreads();
#pragma unroll
    for (int i = 0; i < 4; i++) {
        const int n = wv * 4 + i;
        const float s = part[n][0][lane] + part[n][1][lane] + part[n][2][lane] + part[n][3][lane];
        out[(size_t)(n0 + n) * 64 + lane] = fast_tanh(s + b2[lane]);
    }
}

// ---------------- launcher --------------------------------------------------
extern "C" void kernel_launch(void* const* d_in, const int* in_sizes, int n_in,
                              void* d_out, int out_size, void* d_ws, size_t ws_size,
                              hipStream_t stream)
{
    const float* x         = (const float*)d_in[0];
    const int*   ei        = (const int*)d_in[1];
    const float* edge_attr = (const float*)d_in[2];
    const float* W_l       = (const float*)d_in[3];
    const float* b_l       = (const float*)d_in[4];
    const float* W_r       = (const float*)d_in[5];
    const float* b_r       = (const float*)d_in[6];
    const float* W_e       = (const float*)d_in[7];
    const float* att       = (const float*)d_in[8];
    const float* bias_gat  = (const float*)d_in[9];
    const float* W1        = (const float*)d_in[10];
    const float* b1        = (const float*)d_in[11];
    const float* gamma     = (const float*)d_in[12];
    const float* beta      = (const float*)d_in[13];
    const float* W2        = (const float*)d_in[14];
    const float* b2        = (const float*)d_in[15];
    float* out = (float*)d_out;

    char* wsb = (char*)d_ws;
    size_t o = 0;
    unsigned short* xl_t   = (unsigned short*)(wsb + o);  o += (size_t)N_NODES * HC * 2;
    unsigned short* xr_t   = (unsigned short*)(wsb + o);  o += (size_t)N_NODES * HC * 2;
    unsigned short* ea_csr = (unsigned short*)(wsb + o);  o += (size_t)N_EDGES * 32 * 2;
    int* csr_src           = (int*)(wsb + o);             o += (size_t)N_EDGES * 4;
    int* count             = (int*)(wsb + o);             o += (size_t)N_NODES * 4;
    int* cursor            = (int*)(wsb + o);             o += (size_t)N_NODES * 4;
    int* off               = (int*)(wsb + o);             o += (size_t)(N_NODES + 1) * 4;
    unsigned short* wfrag  = (unsigned short*)(wsb + o);  o += 16 * 64 * 8 * 2;
    unsigned short* att_t  = (unsigned short*)(wsb + o);  o += 256 * 2;
    o = (o + 255) & ~(size_t)255;
    void* zs_g             = (void*)(wsb + o);
    const bool f32ok = (o + (size_t)N_NODES * HC * 4) <= ws_size;

    hipMemsetAsync(count, 0, 2 * (size_t)N_NODES * sizeof(int), stream);

    k_node_transform<<<N_NODES / 8, 256, 0, stream>>>(x, W_l, b_l, W_r, b_r, xl_t, xr_t);
    k_prep<<<1, 256, 0, stream>>>(W_e, att, wfrag, att_t);
    k_hist<<<(N_EDGES + 255) / 256, 256, 0, stream>>>(ei, count);
    k_scan<<<1, 1024, 0, stream>>>(count, off);
    k_scatter<<<(N_EDGES + 255) / 256, 256, 0, stream>>>(ei, off, cursor, edge_attr,
                                                         csr_src, ea_csr);
    if (f32ok) {
        k_edgeagg<true><<<EDGE_BLOCKS, 256, 0, stream>>>(off, csr_src, ea_csr, wfrag, att_t,
                                                         xl_t, xr_t, zs_g);
        k_post<true><<<N_NODES / 16, 256, 0, stream>>>(zs_g, x, bias_gat,
                                                       W1, b1, gamma, beta, W2, b2, out);
    } else {
        k_edgeagg<false><<<EDGE_BLOCKS, 256, 0, stream>>>(off, csr_src, ea_csr, wfrag, att_t,
                                                          xl_t, xr_t, zs_g);
        k_post<false><<<N_NODES / 16, 256, 0, stream>>>(zs_g, x, bias_gat,
                                                        W1, b1, gamma, beta, W2, b2, out);
    }
}

// Round 16
// 616.867 us; speedup vs baseline: 3.3957x; 1.1059x over previous
//
#include <hip/hip_runtime.h>
#include <math.h>

#define N_NODES 50000
#define N_EDGES 800000
#define HID 64
#define HEADS 4
#define HC 256
#define NEG_SLOPE 0.2f
#define LN_EPS 1e-5f
#define EDGE_BLOCKS 2048   // persistent-wave grid for k_edgeagg (8192 waves)

typedef __attribute__((ext_vector_type(8))) short bf16x8;
typedef __attribute__((ext_vector_type(8))) unsigned short u16x8;
typedef __attribute__((ext_vector_type(4))) float f32x4;

__device__ __forceinline__ float bf2f(unsigned short u) {
    return __uint_as_float(((unsigned int)u) << 16);
}
__device__ __forceinline__ unsigned short f2bf(float f) {
    unsigned int u = __float_as_uint(f);
    u = (u + 0x7fffu + ((u >> 16) & 1u)) >> 16;   // RNE
    return (unsigned short)u;
}
__device__ __forceinline__ float fast_tanh(float v) {
    const float c = fminf(fmaxf(v, -15.f), 15.f);
    const float e = __expf(2.f * c);
    return 1.f - 2.f / (e + 1.f);
}

// ---------------- K1: node transform -> TRANSPOSED-TILED bf16 xl_t / xr_t --
__global__ __launch_bounds__(256) void k_node_transform(
    const float* __restrict__ x,
    const float* __restrict__ W_l, const float* __restrict__ b_l,
    const float* __restrict__ W_r, const float* __restrict__ b_r,
    unsigned short* __restrict__ xl_t, unsigned short* __restrict__ xr_t)
{
    __shared__ float xs[8][64];
    __shared__ unsigned short tl[8][256], tr[8][256];
    const int n0 = blockIdx.x * 8;
    const int t = threadIdx.x;
    for (int i = t; i < 8 * 64; i += 256) xs[i >> 6][i & 63] = x[n0 * 64 + i];
    __syncthreads();

    float accl[8], accr[8];
    const float bl = b_l[t], br = b_r[t];
#pragma unroll
    for (int n = 0; n < 8; n++) { accl[n] = bl; accr[n] = br; }
    for (int k = 0; k < 64; k++) {
        const float wl = W_l[k * 256 + t];
        const float wr = W_r[k * 256 + t];
#pragma unroll
        for (int n = 0; n < 8; n++) {
            accl[n] = fmaf(xs[n][k], wl, accl[n]);
            accr[n] = fmaf(xs[n][k], wr, accr[n]);
        }
    }
    const int pos = (t & 15) * 16 + (t >> 4);
#pragma unroll
    for (int n = 0; n < 8; n++) {
        tl[n][pos] = f2bf(accl[n]);
        tr[n][pos] = f2bf(accr[n]);
    }
    __syncthreads();
    const int n = t >> 5, q = t & 31;
    ushort4 v0 = *(const ushort4*)&tl[n][q * 8];
    ushort4 v1 = *(const ushort4*)&tl[n][q * 8 + 4];
    ushort4 w0 = *(const ushort4*)&tr[n][q * 8];
    ushort4 w1 = *(const ushort4*)&tr[n][q * 8 + 4];
    *(ushort4*)(xl_t + (size_t)(n0 + n) * 256 + q * 8)     = v0;
    *(ushort4*)(xl_t + (size_t)(n0 + n) * 256 + q * 8 + 4) = v1;
    *(ushort4*)(xr_t + (size_t)(n0 + n) * 256 + q * 8)     = w0;
    *(ushort4*)(xr_t + (size_t)(n0 + n) * 256 + q * 8 + 4) = w1;
}

// ---------------- K1b: prep W_e B-frags (bf16) + att_t ----------------------
__global__ __launch_bounds__(256) void k_prep(
    const float* __restrict__ W_e, const float* __restrict__ att,
    unsigned short* __restrict__ wfrag, unsigned short* __restrict__ att_t)
{
    const int t = threadIdx.x;
#pragma unroll
    for (int s = 0; s < 4; s++) {
        const int slot = t * 4 + s;
        const int nt = slot >> 6, ls = slot & 63;
        const int col = nt * 16 + (ls & 15);
        const int kb = (ls >> 4) * 8;
#pragma unroll
        for (int j = 0; j < 8; j++)
            wfrag[slot * 8 + j] = f2bf(W_e[(kb + j) * 256 + col]);
    }
    att_t[t] = f2bf(att[(t & 15) * 16 + (t >> 4)]);
}

// ---------------- K2: histogram of dst ------------------------------------
__global__ __launch_bounds__(256) void k_hist(const int* __restrict__ ei, int* __restrict__ count)
{
    const int e = blockIdx.x * 256 + threadIdx.x;
    if (e < N_EDGES) atomicAdd(&count[ei[N_EDGES + e]], 1);
}

// ---------------- K3: exclusive scan (single block) ------------------------
__global__ __launch_bounds__(1024) void k_scan(const int* __restrict__ count, int* __restrict__ off)
{
    __shared__ int wsum[16];
    __shared__ int s_carry;
    const int t = threadIdx.x, lane = t & 63, wv = t >> 6;
    if (t == 0) s_carry = 0;
    __syncthreads();
    for (int base = 0; base < N_NODES; base += 8192) {
        const int idx0 = base + t * 8;
        int v[8];
#pragma unroll
        for (int j = 0; j < 8; j++) { int i = idx0 + j; v[j] = (i < N_NODES) ? count[i] : 0; }
#pragma unroll
        for (int j = 1; j < 8; j++) v[j] += v[j - 1];
        const int tot = v[7];
        int sc = tot;
#pragma unroll
        for (int s = 1; s < 64; s <<= 1) { int o = __shfl_up(sc, s, 64); if (lane >= s) sc += o; }
        if (lane == 63) wsum[wv] = sc;
        __syncthreads();
        const int carry = s_carry;
        int woff = 0;
        for (int u = 0; u < wv; u++) woff += wsum[u];
        const int ebase = carry + woff + (sc - tot);
#pragma unroll
        for (int j = 0; j < 8; j++) {
            int i = idx0 + j;
            if (i < N_NODES) off[i] = ebase + (j ? v[j - 1] : 0);
        }
        __syncthreads();
        if (t == 0) { int tt = 0; for (int u = 0; u < 16; u++) tt += wsum[u]; s_carry = carry + tt; }
        __syncthreads();
    }
    if (threadIdx.x == 0) off[N_NODES] = s_carry;
}

// ---------------- K4: scatter src + PERMUTED bf16 edge_attr into CSR -------
__global__ __launch_bounds__(256) void k_scatter(
    const int* __restrict__ ei, const int* __restrict__ off, int* __restrict__ cursor,
    const float* __restrict__ edge_attr,
    int* __restrict__ csr_src, unsigned short* __restrict__ ea_csr)
{
    const int e = blockIdx.x * 256 + threadIdx.x;
    if (e < N_EDGES) {
        const int s = ei[e];
        const int d = ei[N_EDGES + e];
        const int pos = off[d] + atomicAdd(&cursor[d], 1);
        csr_src[pos] = s;
        const float4* src4 = (const float4*)(edge_attr + (size_t)e * 32);
        ushort4* dst4 = (ushort4*)(ea_csr + (size_t)pos * 32);
#pragma unroll
        for (int i = 0; i < 8; i++) {
            const float4 v = src4[i];
            ushort4 u;
            u.x = f2bf(v.x); u.y = f2bf(v.y); u.z = f2bf(v.z); u.w = f2bf(v.w);
            dst4[i] = u;
        }
    }
}

// ---------------- K5: edge+aggregate, persistent waves, 1-deep pipeline ----
// Wave = sequence of nodes (grid-stride). While computing tile i, tile i+1's
// state (csr_src/ea at tile top; xl gathers at mid-tile; next node's off/xr
// a full node ahead) is prefetched. All pipeline branches are wave-uniform.
template<bool F32>
__global__ __launch_bounds__(256) void k_edgeagg(
    const int* __restrict__ off, const int* __restrict__ csr_src,
    const unsigned short* __restrict__ ea_csr,
    const unsigned short* __restrict__ wfrag, const unsigned short* __restrict__ att_t,
    const unsigned short* __restrict__ xl_t, const unsigned short* __restrict__ xr_t,
    void* __restrict__ zs_g)
{
    __shared__ unsigned short bfrag_s[16][64][8];   // 16 KB, only LDS

    const int t = threadIdx.x;
    const int lane = t & 63, wv = t >> 6;
    const int arow = lane & 15, koct = lane >> 4;

    for (int i = t; i < 1024; i += 256)
        *(u16x8*)&bfrag_s[i >> 6][i & 63][0] = *(const u16x8*)(wfrag + i * 8);
    __syncthreads();

    const u16x8 attL = *(const u16x8*)(att_t + arow * 16);
    const u16x8 attH = *(const u16x8*)(att_t + arow * 16 + 8);

    const int STRIDE = EDGE_BLOCKS * 4;
    int node = blockIdx.x * 4 + wv;
    if (node >= N_NODES) return;

    // ---- current node context ----
    int lo = off[node], hi = off[node + 1];
    u16x8 xrl = *(const u16x8*)(xr_t + (size_t)node * 256 + arow * 16);
    u16x8 xrh = *(const u16x8*)(xr_t + (size_t)node * 256 + arow * 16 + 8);
    while (hi <= lo) {                    // degree-0 node (rare): zeros, advance
#pragma unroll
        for (int q = 0; q < 4; q++) {
            const int nt = koct * 4 + q;
            if (F32) ((float*)zs_g)[(size_t)node * 256 + nt * 16 + arow] = 0.f;
            else ((unsigned short*)zs_g)[(size_t)node * 256 + nt * 16 + arow] = 0;
        }
        node += STRIDE;
        if (node >= N_NODES) return;
        lo = off[node]; hi = off[node + 1];
        xrl = *(const u16x8*)(xr_t + (size_t)node * 256 + arow * 16);
        xrh = *(const u16x8*)(xr_t + (size_t)node * 256 + arow * 16 + 8);
    }
    // ---- prefetch next node context ----
    int nnode = node + STRIDE;
    bool nvalid = nnode < N_NODES;
    int nlo = 0, nhi = 0;
    u16x8 nxrl = xrl, nxrh = xrh;
    if (nvalid) {
        nlo = off[nnode]; nhi = off[nnode + 1];
        nxrl = *(const u16x8*)(xr_t + (size_t)nnode * 256 + arow * 16);
        nxrh = *(const u16x8*)(xr_t + (size_t)nnode * 256 + arow * 16 + 8);
    }
    // ---- first tile chain (cold) ----
    int p0 = lo;
    bf16x8 af;
    u16x8 xlo[4], xhi[4];
    {
        const int pa = min(p0 + arow, hi - 1);
        const int sv0 = csr_src[pa];
        af = *(const bf16x8*)(ea_csr + (size_t)pa * 32 + koct * 8);
#pragma unroll
        for (int r = 0; r < 4; r++) {
            const int sr = __shfl(sv0, koct * 4 + r, 64);
            const unsigned short* bp = xl_t + (size_t)sr * 256 + arow * 16;
            xlo[r] = *(const u16x8*)bp;
            xhi[r] = *(const u16x8*)(bp + 8);
        }
    }

    float g[16];
#pragma unroll
    for (int i = 0; i < 16; i++) g[i] = 0.f;
    float dsum[4] = {0.f, 0.f, 0.f, 0.f};

    for (;;) {
        const bool last = (p0 + 16 >= hi);
        // ---- identify upcoming tile; issue its sv/af loads ----
        bool uvalid;
        int up0, uhic;
        if (!last) { uvalid = true; up0 = p0 + 16; uhic = hi; }
        else {
            while (nvalid && nlo >= nhi) {   // skip empty next nodes (rare)
#pragma unroll
                for (int q = 0; q < 4; q++) {
                    const int nt = koct * 4 + q;
                    if (F32) ((float*)zs_g)[(size_t)nnode * 256 + nt * 16 + arow] = 0.f;
                    else ((unsigned short*)zs_g)[(size_t)nnode * 256 + nt * 16 + arow] = 0;
                }
                nnode += STRIDE;
                nvalid = nnode < N_NODES;
                if (nvalid) {
                    nlo = off[nnode]; nhi = off[nnode + 1];
                    nxrl = *(const u16x8*)(xr_t + (size_t)nnode * 256 + arow * 16);
                    nxrh = *(const u16x8*)(xr_t + (size_t)nnode * 256 + arow * 16 + 8);
                }
            }
            uvalid = nvalid; up0 = nlo; uhic = nhi;
        }
        int usv = 0;
        bf16x8 uaf = af;
        if (uvalid) {
            const int upa = min(up0 + arow, uhic - 1);
            usv = csr_src[upa];
            uaf = *(const bf16x8*)(ea_csr + (size_t)upa * 32 + koct * 8);
        }

        // ---- compute current tile: nt 0..7 (xlo half) ----
        float s_[4][4];
#pragma unroll
        for (int r = 0; r < 4; r++)
#pragma unroll
            for (int h = 0; h < 4; h++) s_[r][h] = 0.f;

#pragma unroll
        for (int nt = 0; nt < 8; nt++) {
            const bf16x8 bfr = *(const bf16x8*)&bfrag_s[nt][lane][0];
            f32x4 dacc = {0.f, 0.f, 0.f, 0.f};
            dacc = __builtin_amdgcn_mfma_f32_16x16x32_bf16(af, bfr, dacc, 0, 0, 0);
            const float xrv = bf2f((unsigned short)xrl[nt]);
            const float atv = bf2f((unsigned short)attL[nt]);
            const int h = nt >> 2;
#pragma unroll
            for (int r = 0; r < 4; r++) {
                const float xv = bf2f((unsigned short)xlo[r][nt]);
                float mm = dacc[r] + xv + xrv;
                mm = (mm > 0.f) ? mm : NEG_SLOPE * mm;
                s_[r][h] = fmaf(atv, mm, s_[r][h]);
            }
        }
        // ---- mid-tile: shfl prefetched sv, issue upcoming xl gathers ----
        u16x8 uxlo[4], uxhi[4];
        if (uvalid) {
#pragma unroll
            for (int r = 0; r < 4; r++) {
                const int sr = __shfl(usv, koct * 4 + r, 64);
                const unsigned short* bp = xl_t + (size_t)sr * 256 + arow * 16;
                uxlo[r] = *(const u16x8*)bp;
                uxhi[r] = *(const u16x8*)(bp + 8);
            }
        } else {
#pragma unroll
            for (int r = 0; r < 4; r++) { uxlo[r] = xlo[r]; uxhi[r] = xhi[r]; }
        }
        // ---- nt 8..15 (xhi half) ----
#pragma unroll
        for (int n2 = 0; n2 < 8; n2++) {
            const int nt = n2 + 8;
            const bf16x8 bfr = *(const bf16x8*)&bfrag_s[nt][lane][0];
            f32x4 dacc = {0.f, 0.f, 0.f, 0.f};
            dacc = __builtin_amdgcn_mfma_f32_16x16x32_bf16(af, bfr, dacc, 0, 0, 0);
            const float xrv = bf2f((unsigned short)xrh[n2]);
            const float atv = bf2f((unsigned short)attH[n2]);
            const int h = nt >> 2;
#pragma unroll
            for (int r = 0; r < 4; r++) {
                const float xv = bf2f((unsigned short)xhi[r][n2]);
                float mm = dacc[r] + xv + xrv;
                mm = (mm > 0.f) ? mm : NEG_SLOPE * mm;
                s_[r][h] = fmaf(atv, mm, s_[r][h]);
            }
        }
        // ---- logit reduce over 16 arow lanes ----
#pragma unroll
        for (int r = 0; r < 4; r++)
#pragma unroll
            for (int h = 0; h < 4; h++) {
                float v = s_[r][h];
                v += __shfl_xor(v, 1, 64);
                v += __shfl_xor(v, 2, 64);
                v += __shfl_xor(v, 4, 64);
                v += __shfl_xor(v, 8, 64);
                s_[r][h] = v;
            }
        // ---- exp + aggregate ----
#pragma unroll
        for (int h = 0; h < 4; h++) {
            float w4[4];
#pragma unroll
            for (int r = 0; r < 4; r++) {
                const bool ok = (p0 + koct * 4 + r) < hi;
                w4[r] = ok ? __expf(fminf(s_[r][h], 60.f)) : 0.f;
            }
            dsum[h] += (w4[0] + w4[1]) + (w4[2] + w4[3]);
#pragma unroll
            for (int q = 0; q < 4; q++) {
                const int nt = h * 4 + q;
                float acc = g[nt];
#pragma unroll
                for (int r = 0; r < 4; r++) {
                    const float xv = bf2f((unsigned short)(nt < 8 ? xlo[r][nt & 7] : xhi[r][nt & 7]));
                    acc = fmaf(w4[r], xv, acc);
                }
                g[nt] = acc;
            }
        }

        // ---- node boundary: reduce + write, rotate node ctx ----
        if (last) {
#pragma unroll
            for (int i = 0; i < 16; i++) {
                float v = g[i];
                v += __shfl_xor(v, 16, 64);
                v += __shfl_xor(v, 32, 64);
                g[i] = v;
            }
#pragma unroll
            for (int h = 0; h < 4; h++) {
                float v = dsum[h];
                v += __shfl_xor(v, 16, 64);
                v += __shfl_xor(v, 32, 64);
                dsum[h] = v;
            }
            float inv[4];
#pragma unroll
            for (int h = 0; h < 4; h++) inv[h] = 1.f / (dsum[h] + 1e-16f);
#pragma unroll
            for (int q = 0; q < 4; q++) {
                const int nt = koct * 4 + q;
                const float v = g[nt] * inv[nt >> 2];
                if (F32) ((float*)zs_g)[(size_t)node * 256 + nt * 16 + arow] = v;
                else ((unsigned short*)zs_g)[(size_t)node * 256 + nt * 16 + arow] = f2bf(v);
            }
            if (!uvalid) return;   // wave done
            node = nnode; lo = nlo; hi = nhi; xrl = nxrl; xrh = nxrh;
#pragma unroll
            for (int i = 0; i < 16; i++) g[i] = 0.f;
#pragma unroll
            for (int h = 0; h < 4; h++) dsum[h] = 0.f;
            nnode += STRIDE;
            nvalid = nnode < N_NODES;
            if (nvalid) {
                nlo = off[nnode]; nhi = off[nnode + 1];
                nxrl = *(const u16x8*)(xr_t + (size_t)nnode * 256 + arow * 16);
                nxrh = *(const u16x8*)(xr_t + (size_t)nnode * 256 + arow * 16 + 8);
            }
        }
        // ---- rotate tile state ----
        p0 = up0;
        af = uaf;
#pragma unroll
        for (int r = 0; r < 4; r++) { xlo[r] = uxlo[r]; xhi[r] = uxhi[r]; }
    }
}

// ---------------- K6: epilogue (MLP + LN + out-GEMM), 16 nodes/block -------
template<bool F32>
__global__ __launch_bounds__(256) void k_post(
    const void* __restrict__ zs_g, const float* __restrict__ x,
    const float* __restrict__ bias_gat,
    const float* __restrict__ W1, const float* __restrict__ b1,
    const float* __restrict__ gamma, const float* __restrict__ beta,
    const float* __restrict__ W2, const float* __restrict__ b2,
    float* __restrict__ out)
{
    __shared__ float xs[16][64];
    __shared__ float zsh[16][256];
    __shared__ float part[16][4][64];
    __shared__ float redS[16][4], redQ[16][4];

    const int n0 = blockIdx.x * 16;
    const int t = threadIdx.x, lane = t & 63, wv = t >> 6;

    for (int i = t; i < 16 * 64; i += 256) xs[i >> 6][i & 63] = x[n0 * 64 + i];
    __syncthreads();

    float a1[16];
    const float b1v = b1[t];
#pragma unroll
    for (int n = 0; n < 16; n++) a1[n] = b1v;
    for (int k = 0; k < 64; k++) {
        const float w1v = W1[k * 256 + t];
#pragma unroll
        for (int n = 0; n < 16; n++) a1[n] = fmaf(xs[n][k], w1v, a1[n]);
    }

    const float bg = bias_gat[t];
    float z[16];
#pragma unroll
    for (int n = 0; n < 16; n++) {
        const float gv = F32 ? ((const float*)zs_g)[(size_t)(n0 + n) * 256 + t]
                             : bf2f(((const unsigned short*)zs_g)[(size_t)(n0 + n) * 256 + t]);
        z[n] = fast_tanh(a1[n]) + gv + bg;
    }

    const float gm = gamma[t], bt = beta[t];
#pragma unroll
    for (int n = 0; n < 16; n++) {
        float s = z[n], q = z[n] * z[n];
#pragma unroll
        for (int m = 1; m < 64; m <<= 1) { s += __shfl_xor(s, m, 64); q += __shfl_xor(q, m, 64); }
        if (lane == 0) { redS[n][wv] = s; redQ[n][wv] = q; }
    }
    __syncthreads();
#pragma unroll
    for (int n = 0; n < 16; n++) {
        const float s = redS[n][0] + redS[n][1] + redS[n][2] + redS[n][3];
        const float q = redQ[n][0] + redQ[n][1] + redQ[n][2] + redQ[n][3];
        const float mu = s * (1.f / 256.f);
        const float var = q * (1.f / 256.f) - mu * mu;
        const float ivn = rsqrtf(var + LN_EPS);
        zsh[n][t] = (z[n] - mu) * ivn * gm + bt;
    }
    __syncthreads();

    const int j = t & 63, qq = t >> 6;
    float p[16];
#pragma unroll
    for (int n = 0; n < 16; n++) p[n] = 0.f;
    for (int c0 = 0; c0 < 64; c0++) {
        const int c = qq * 64 + c0;
        const float w2v = W2[c * 64 + j];
#pragma unroll
        for (int n = 0; n < 16; n++) p[n] = fmaf(zsh[n][c], w2v, p[n]);
    }
#pragma unroll
    for (int n = 0; n < 16; n++) part[n][qq][j] = p[n];
    __syncthreads();
#pragma unroll
    for (int i = 0; i < 4; i++) {
        const int n = wv * 4 + i;
        const float s = part[n][0][lane] + part[n][1][lane] + part[n][2][lane] + part[n][3][lane];
        out[(size_t)(n0 + n) * 64 + lane] = fast_tanh(s + b2[lane]);
    }
}

// ---------------- launcher --------------------------------------------------
extern "C" void kernel_launch(void* const* d_in, const int* in_sizes, int n_in,
                              void* d_out, int out_size, void* d_ws, size_t ws_size,
                              hipStream_t stream)
{
    const float* x         = (const float*)d_in[0];
    const int*   ei        = (const int*)d_in[1];
    const float* edge_attr = (const float*)d_in[2];
    const float* W_l       = (const float*)d_in[3];
    const float* b_l       = (const float*)d_in[4];
    const float* W_r       = (const float*)d_in[5];
    const float* b_r       = (const float*)d_in[6];
    const float* W_e       = (const float*)d_in[7];
    const float* att       = (const float*)d_in[8];
    const float* bias_gat  = (const float*)d_in[9];
    const float* W1        = (const float*)d_in[10];
    const float* b1        = (const float*)d_in[11];
    const float* gamma     = (const float*)d_in[12];
    const float* beta      = (const float*)d_in[13];
    const float* W2        = (const float*)d_in[14];
    const float* b2        = (const float*)d_in[15];
    float* out = (float*)d_out;

    char* wsb = (char*)d_ws;
    size_t o = 0;
    unsigned short* xl_t   = (unsigned short*)(wsb + o);  o += (size_t)N_NODES * HC * 2;
    unsigned short* xr_t   = (unsigned short*)(wsb + o);  o += (size_t)N_NODES * HC * 2;
    unsigned short* ea_csr = (unsigned short*)(wsb + o);  o += (size_t)N_EDGES * 32 * 2;
    int* csr_src           = (int*)(wsb + o);             o += (size_t)N_EDGES * 4;
    int* count             = (int*)(wsb + o);             o += (size_t)N_NODES * 4;
    int* cursor            = (int*)(wsb + o);             o += (size_t)N_NODES * 4;
    int* off               = (int*)(wsb + o);             o += (size_t)(N_NODES + 1) * 4;
    unsigned short* wfrag  = (unsigned short*)(wsb + o);  o += 16 * 64 * 8 * 2;
    unsigned short* att_t  = (unsigned short*)(wsb + o);  o += 256 * 2;
    o = (o + 255) & ~(size_t)255;
    void* zs_g             = (void*)(wsb + o);
    const bool f32ok = (o + (size_t)N_NODES * HC * 4) <= ws_size;

    hipMemsetAsync(count, 0, 2 * (size_t)N_NODES * sizeof(int), stream);

    k_node_transform<<<N_NODES / 8, 256, 0, stream>>>(x, W_l, b_l, W_r, b_r, xl_t, xr_t);
    k_prep<<<1, 256, 0, stream>>>(W_e, att, wfrag, att_t);
    k_hist<<<(N_EDGES + 255) / 256, 256, 0, stream>>>(ei, count);
    k_scan<<<1, 1024, 0, stream>>>(count, off);
    k_scatter<<<(N_EDGES + 255) / 256, 256, 0, stream>>>(ei, off, cursor, edge_attr,
                                                         csr_src, ea_csr);
    if (f32ok) {
        k_edgeagg<true><<<EDGE_BLOCKS, 256, 0, stream>>>(off, csr_src, ea_csr, wfrag, att_t,
                                                         xl_t, xr_t, zs_g);
        k_post<true><<<N_NODES / 16, 256, 0, stream>>>(zs_g, x, bias_gat,
                                                       W1, b1, gamma, beta, W2, b2, out);
    } else {
        k_edgeagg<false><<<EDGE_BLOCKS, 256, 0, stream>>>(off, csr_src, ea_csr, wfrag, att_t,
                                                          xl_t, xr_t, zs_g);
        k_post<false><<<N_NODES / 16, 256, 0, stream>>>(zs_g, x, bias_gat,
                                                        W1, b1, gamma, beta, W2, b2, out);
    }
}

// Round 17
// 598.147 us; speedup vs baseline: 3.5020x; 1.0313x over previous
//
#include <hip/hip_runtime.h>
#include <math.h>

#define N_NODES 50000
#define N_EDGES 800000
#define HID 64
#define HEADS 4
#define HC 256
#define NEG_SLOPE 0.2f
#define LN_EPS 1e-5f
#define EDGE_BLOCKS 2048   // persistent-wave grid for k_edgeagg (8192 waves)

typedef __attribute__((ext_vector_type(8))) short bf16x8;
typedef __attribute__((ext_vector_type(8))) unsigned short u16x8;
typedef __attribute__((ext_vector_type(4))) float f32x4;

__device__ __forceinline__ float bf2f(unsigned short u) {
    return __uint_as_float(((unsigned int)u) << 16);
}
__device__ __forceinline__ unsigned short f2bf(float f) {
    unsigned int u = __float_as_uint(f);
    u = (u + 0x7fffu + ((u >> 16) & 1u)) >> 16;   // RNE
    return (unsigned short)u;
}
__device__ __forceinline__ float fast_tanh(float v) {
    const float c = fminf(fmaxf(v, -15.f), 15.f);
    const float e = __expf(2.f * c);
    return 1.f - 2.f / (e + 1.f);
}

// ---------------- K1: node transform -> TRANSPOSED-TILED bf16 (16 nodes/blk)
__global__ __launch_bounds__(256) void k_node_transform(
    const float* __restrict__ x,
    const float* __restrict__ W_l, const float* __restrict__ b_l,
    const float* __restrict__ W_r, const float* __restrict__ b_r,
    unsigned short* __restrict__ xl_t, unsigned short* __restrict__ xr_t)
{
    __shared__ float xs[16][64];
    __shared__ unsigned short tl[16][256], tr[16][256];
    const int n0 = blockIdx.x * 16;
    const int t = threadIdx.x;
    for (int i = t; i < 16 * 64; i += 256) xs[i >> 6][i & 63] = x[n0 * 64 + i];
    __syncthreads();

    float accl[16], accr[16];
    const float bl = b_l[t], br = b_r[t];
#pragma unroll
    for (int n = 0; n < 16; n++) { accl[n] = bl; accr[n] = br; }
    for (int k = 0; k < 64; k++) {
        const float wl = W_l[k * 256 + t];
        const float wr = W_r[k * 256 + t];
#pragma unroll
        for (int n = 0; n < 16; n++) {
            accl[n] = fmaf(xs[n][k], wl, accl[n]);
            accr[n] = fmaf(xs[n][k], wr, accr[n]);
        }
    }
    const int pos = (t & 15) * 16 + (t >> 4);
#pragma unroll
    for (int n = 0; n < 16; n++) {
        tl[n][pos] = f2bf(accl[n]);
        tr[n][pos] = f2bf(accr[n]);
    }
    __syncthreads();
    // write-out: thread t -> node t>>4, 16 ushorts at (t&15)*16
    const int n = t >> 4, q = t & 15;
#pragma unroll
    for (int i = 0; i < 4; i++) {
        *(ushort4*)(xl_t + (size_t)(n0 + n) * 256 + q * 16 + i * 4) = *(const ushort4*)&tl[n][q * 16 + i * 4];
        *(ushort4*)(xr_t + (size_t)(n0 + n) * 256 + q * 16 + i * 4) = *(const ushort4*)&tr[n][q * 16 + i * 4];
    }
}

// ---------------- K1b: prep W_e B-frags (bf16) + att_t ----------------------
__global__ __launch_bounds__(256) void k_prep(
    const float* __restrict__ W_e, const float* __restrict__ att,
    unsigned short* __restrict__ wfrag, unsigned short* __restrict__ att_t)
{
    const int t = threadIdx.x;
#pragma unroll
    for (int s = 0; s < 4; s++) {
        const int slot = t * 4 + s;
        const int nt = slot >> 6, ls = slot & 63;
        const int col = nt * 16 + (ls & 15);
        const int kb = (ls >> 4) * 8;
#pragma unroll
        for (int j = 0; j < 8; j++)
            wfrag[slot * 8 + j] = f2bf(W_e[(kb + j) * 256 + col]);
    }
    att_t[t] = f2bf(att[(t & 15) * 16 + (t >> 4)]);
}

// ---------------- K2: histogram of dst ------------------------------------
__global__ __launch_bounds__(256) void k_hist(const int* __restrict__ ei, int* __restrict__ count)
{
    const int e = blockIdx.x * 256 + threadIdx.x;
    if (e < N_EDGES) atomicAdd(&count[ei[N_EDGES + e]], 1);
}

// ---------------- K3: exclusive scan (single block) ------------------------
__global__ __launch_bounds__(1024) void k_scan(const int* __restrict__ count, int* __restrict__ off)
{
    __shared__ int wsum[16];
    __shared__ int s_carry;
    const int t = threadIdx.x, lane = t & 63, wv = t >> 6;
    if (t == 0) s_carry = 0;
    __syncthreads();
    for (int base = 0; base < N_NODES; base += 8192) {
        const int idx0 = base + t * 8;
        int v[8];
#pragma unroll
        for (int j = 0; j < 8; j++) { int i = idx0 + j; v[j] = (i < N_NODES) ? count[i] : 0; }
#pragma unroll
        for (int j = 1; j < 8; j++) v[j] += v[j - 1];
        const int tot = v[7];
        int sc = tot;
#pragma unroll
        for (int s = 1; s < 64; s <<= 1) { int o = __shfl_up(sc, s, 64); if (lane >= s) sc += o; }
        if (lane == 63) wsum[wv] = sc;
        __syncthreads();
        const int carry = s_carry;
        int woff = 0;
        for (int u = 0; u < wv; u++) woff += wsum[u];
        const int ebase = carry + woff + (sc - tot);
#pragma unroll
        for (int j = 0; j < 8; j++) {
            int i = idx0 + j;
            if (i < N_NODES) off[i] = ebase + (j ? v[j - 1] : 0);
        }
        __syncthreads();
        if (t == 0) { int tt = 0; for (int u = 0; u < 16; u++) tt += wsum[u]; s_carry = carry + tt; }
        __syncthreads();
    }
    if (threadIdx.x == 0) off[N_NODES] = s_carry;
}

// ---------------- K4: scatter src + PERMUTED bf16 edge_attr into CSR -------
__global__ __launch_bounds__(256) void k_scatter(
    const int* __restrict__ ei, const int* __restrict__ off, int* __restrict__ cursor,
    const float* __restrict__ edge_attr,
    int* __restrict__ csr_src, unsigned short* __restrict__ ea_csr)
{
    const int e = blockIdx.x * 256 + threadIdx.x;
    if (e < N_EDGES) {
        const int s = ei[e];
        const int d = ei[N_EDGES + e];
        const int pos = off[d] + atomicAdd(&cursor[d], 1);
        csr_src[pos] = s;
        const float4* src4 = (const float4*)(edge_attr + (size_t)e * 32);
        ushort4* dst4 = (ushort4*)(ea_csr + (size_t)pos * 32);
#pragma unroll
        for (int i = 0; i < 8; i++) {
            const float4 v = src4[i];
            ushort4 u;
            u.x = f2bf(v.x); u.y = f2bf(v.y); u.z = f2bf(v.z); u.w = f2bf(v.w);
            dst4[i] = u;
        }
    }
}

// ---------------- K5: edge+aggregate, persistent waves, deep pipeline ------
// Wave = sequence of nodes. Per-NODE src vector (svall covers 64 CSR slots;
// next node's nsvall prefetched a full node ahead) removes the per-tile
// csr_src load from the critical chain. xr folded into the MFMA C-operand.
template<bool F32>
__global__ __launch_bounds__(256) void k_edgeagg(
    const int* __restrict__ off, const int* __restrict__ csr_src,
    const unsigned short* __restrict__ ea_csr,
    const unsigned short* __restrict__ wfrag, const unsigned short* __restrict__ att_t,
    const unsigned short* __restrict__ xl_t, const unsigned short* __restrict__ xr_t,
    void* __restrict__ zs_g)
{
    __shared__ unsigned short bfrag_s[16][64][8];   // 16 KB, only LDS

    const int t = threadIdx.x;
    const int lane = t & 63, wv = t >> 6;
    const int arow = lane & 15, koct = lane >> 4;

    for (int i = t; i < 1024; i += 256)
        *(u16x8*)&bfrag_s[i >> 6][i & 63][0] = *(const u16x8*)(wfrag + i * 8);
    __syncthreads();

    const u16x8 attL = *(const u16x8*)(att_t + arow * 16);
    const u16x8 attH = *(const u16x8*)(att_t + arow * 16 + 8);

    const int STRIDE = EDGE_BLOCKS * 4;
    int node = blockIdx.x * 4 + wv;
    if (node >= N_NODES) return;

    // ---- current node context ----
    int lo = off[node], hi = off[node + 1];
    u16x8 xrl = *(const u16x8*)(xr_t + (size_t)node * 256 + arow * 16);
    u16x8 xrh = *(const u16x8*)(xr_t + (size_t)node * 256 + arow * 16 + 8);
    while (hi <= lo) {                    // degree-0 node (rare): zeros, advance
#pragma unroll
        for (int q = 0; q < 4; q++) {
            const int nt = koct * 4 + q;
            if (F32) ((float*)zs_g)[(size_t)node * 256 + nt * 16 + arow] = 0.f;
            else ((unsigned short*)zs_g)[(size_t)node * 256 + nt * 16 + arow] = 0;
        }
        node += STRIDE;
        if (node >= N_NODES) return;
        lo = off[node]; hi = off[node + 1];
        xrl = *(const u16x8*)(xr_t + (size_t)node * 256 + arow * 16);
        xrh = *(const u16x8*)(xr_t + (size_t)node * 256 + arow * 16 + 8);
    }
    int svbase = lo;
    int svall = csr_src[min(svbase + lane, hi - 1)];   // covers 64 CSR slots

    // ---- prefetch next node context (incl. its src vector) ----
    int nnode = node + STRIDE;
    bool nvalid = nnode < N_NODES;
    int nlo = 0, nhi = 0, nsvall = 0;
    u16x8 nxrl = xrl, nxrh = xrh;
    if (nvalid) {
        nlo = off[nnode]; nhi = off[nnode + 1];
        nxrl = *(const u16x8*)(xr_t + (size_t)nnode * 256 + arow * 16);
        nxrh = *(const u16x8*)(xr_t + (size_t)nnode * 256 + arow * 16 + 8);
        if (nhi > nlo) nsvall = csr_src[min(nlo + lane, nhi - 1)];
    }
    // ---- first tile chain (cold) ----
    int p0 = lo;
    bf16x8 af;
    u16x8 xlo[4], xhi[4];
    {
        af = *(const bf16x8*)(ea_csr + (size_t)min(p0 + arow, hi - 1) * 32 + koct * 8);
#pragma unroll
        for (int r = 0; r < 4; r++) {
            const int sr = __shfl(svall, koct * 4 + r, 64);
            const unsigned short* bp = xl_t + (size_t)sr * 256 + arow * 16;
            xlo[r] = *(const u16x8*)bp;
            xhi[r] = *(const u16x8*)(bp + 8);
        }
    }

    float g[16];
#pragma unroll
    for (int i = 0; i < 16; i++) g[i] = 0.f;
    float dsum[4] = {0.f, 0.f, 0.f, 0.f};

    for (;;) {
        const bool last = (p0 + 16 >= hi);
        // ---- identify upcoming tile; issue its af load ----
        bool uvalid;
        int up0, uhic;
        if (!last) { uvalid = true; up0 = p0 + 16; uhic = hi; }
        else {
            while (nvalid && nlo >= nhi) {   // skip empty next nodes (rare)
#pragma unroll
                for (int q = 0; q < 4; q++) {
                    const int nt = koct * 4 + q;
                    if (F32) ((float*)zs_g)[(size_t)nnode * 256 + nt * 16 + arow] = 0.f;
                    else ((unsigned short*)zs_g)[(size_t)nnode * 256 + nt * 16 + arow] = 0;
                }
                nnode += STRIDE;
                nvalid = nnode < N_NODES;
                if (nvalid) {
                    nlo = off[nnode]; nhi = off[nnode + 1];
                    nxrl = *(const u16x8*)(xr_t + (size_t)nnode * 256 + arow * 16);
                    nxrh = *(const u16x8*)(xr_t + (size_t)nnode * 256 + arow * 16 + 8);
                    if (nhi > nlo) nsvall = csr_src[min(nlo + lane, nhi - 1)];
                }
            }
            uvalid = nvalid; up0 = nlo; uhic = nhi;
        }
        bf16x8 uaf = af;
        if (uvalid)
            uaf = *(const bf16x8*)(ea_csr + (size_t)min(up0 + arow, uhic - 1) * 32 + koct * 8);

        // ---- compute current tile: nt 0..7 (xlo half), xr folded into C ----
        float s_[4][4];
#pragma unroll
        for (int r = 0; r < 4; r++)
#pragma unroll
            for (int h = 0; h < 4; h++) s_[r][h] = 0.f;

#pragma unroll
        for (int nt = 0; nt < 8; nt++) {
            const bf16x8 bfr = *(const bf16x8*)&bfrag_s[nt][lane][0];
            const float xrv = bf2f((unsigned short)xrl[nt]);
            f32x4 dacc = {xrv, xrv, xrv, xrv};
            dacc = __builtin_amdgcn_mfma_f32_16x16x32_bf16(af, bfr, dacc, 0, 0, 0);
            const float atv = bf2f((unsigned short)attL[nt]);
            const int h = nt >> 2;
#pragma unroll
            for (int r = 0; r < 4; r++) {
                const float mm = dacc[r] + bf2f((unsigned short)xlo[r][nt]);
                const float lk = fmaxf(mm, NEG_SLOPE * mm);
                s_[r][h] = fmaf(atv, lk, s_[r][h]);
            }
        }
        // ---- mid-tile: shfl in-register src vector, issue upcoming gathers --
        u16x8 uxlo[4], uxhi[4];
        if (uvalid) {
            const int ubase = last ? 0 : (up0 - svbase);
            const int usrcv = last ? nsvall : svall;
#pragma unroll
            for (int r = 0; r < 4; r++) {
                const int sr = __shfl(usrcv, ubase + koct * 4 + r, 64);
                const unsigned short* bp = xl_t + (size_t)sr * 256 + arow * 16;
                uxlo[r] = *(const u16x8*)bp;
                uxhi[r] = *(const u16x8*)(bp + 8);
            }
        } else {
#pragma unroll
            for (int r = 0; r < 4; r++) { uxlo[r] = xlo[r]; uxhi[r] = xhi[r]; }
        }
        // ---- nt 8..15 (xhi half) ----
#pragma unroll
        for (int n2 = 0; n2 < 8; n2++) {
            const int nt = n2 + 8;
            const bf16x8 bfr = *(const bf16x8*)&bfrag_s[nt][lane][0];
            const float xrv = bf2f((unsigned short)xrh[n2]);
            f32x4 dacc = {xrv, xrv, xrv, xrv};
            dacc = __builtin_amdgcn_mfma_f32_16x16x32_bf16(af, bfr, dacc, 0, 0, 0);
            const float atv = bf2f((unsigned short)attH[n2]);
            const int h = nt >> 2;
#pragma unroll
            for (int r = 0; r < 4; r++) {
                const float mm = dacc[r] + bf2f((unsigned short)xhi[r][n2]);
                const float lk = fmaxf(mm, NEG_SLOPE * mm);
                s_[r][h] = fmaf(atv, lk, s_[r][h]);
            }
        }
        // ---- logit reduce over 16 arow lanes ----
#pragma unroll
        for (int r = 0; r < 4; r++)
#pragma unroll
            for (int h = 0; h < 4; h++) {
                float v = s_[r][h];
                v += __shfl_xor(v, 1, 64);
                v += __shfl_xor(v, 2, 64);
                v += __shfl_xor(v, 4, 64);
                v += __shfl_xor(v, 8, 64);
                s_[r][h] = v;
            }
        // ---- exp + aggregate ----
#pragma unroll
        for (int h = 0; h < 4; h++) {
            float w4[4];
#pragma unroll
            for (int r = 0; r < 4; r++) {
                const bool ok = (p0 + koct * 4 + r) < hi;
                w4[r] = ok ? __expf(fminf(s_[r][h], 60.f)) : 0.f;
            }
            dsum[h] += (w4[0] + w4[1]) + (w4[2] + w4[3]);
#pragma unroll
            for (int q = 0; q < 4; q++) {
                const int nt = h * 4 + q;
                float acc = g[nt];
#pragma unroll
                for (int r = 0; r < 4; r++) {
                    const float xv = bf2f((unsigned short)(nt < 8 ? xlo[r][nt & 7] : xhi[r][nt & 7]));
                    acc = fmaf(w4[r], xv, acc);
                }
                g[nt] = acc;
            }
        }

        // ---- node boundary: reduce + write, rotate node ctx ----
        if (last) {
#pragma unroll
            for (int i = 0; i < 16; i++) {
                float v = g[i];
                v += __shfl_xor(v, 16, 64);
                v += __shfl_xor(v, 32, 64);
                g[i] = v;
            }
#pragma unroll
            for (int h = 0; h < 4; h++) {
                float v = dsum[h];
                v += __shfl_xor(v, 16, 64);
                v += __shfl_xor(v, 32, 64);
                dsum[h] = v;
            }
            float inv[4];
#pragma unroll
            for (int h = 0; h < 4; h++) inv[h] = 1.f / (dsum[h] + 1e-16f);
#pragma unroll
            for (int q = 0; q < 4; q++) {
                const int nt = koct * 4 + q;
                const float v = g[nt] * inv[nt >> 2];
                if (F32) ((float*)zs_g)[(size_t)node * 256 + nt * 16 + arow] = v;
                else ((unsigned short*)zs_g)[(size_t)node * 256 + nt * 16 + arow] = f2bf(v);
            }
            if (!uvalid) return;   // wave done
            node = nnode; lo = nlo; hi = nhi; xrl = nxrl; xrh = nxrh;
            svbase = nlo; svall = nsvall;
#pragma unroll
            for (int i = 0; i < 16; i++) g[i] = 0.f;
#pragma unroll
            for (int h = 0; h < 4; h++) dsum[h] = 0.f;
            nnode += STRIDE;
            nvalid = nnode < N_NODES;
            if (nvalid) {
                nlo = off[nnode]; nhi = off[nnode + 1];
                nxrl = *(const u16x8*)(xr_t + (size_t)nnode * 256 + arow * 16);
                nxrh = *(const u16x8*)(xr_t + (size_t)nnode * 256 + arow * 16 + 8);
                if (nhi > nlo) nsvall = csr_src[min(nlo + lane, nhi - 1)];
            }
        }
        // ---- rotate tile state ----
        p0 = up0;
        af = uaf;
#pragma unroll
        for (int r = 0; r < 4; r++) { xlo[r] = uxlo[r]; xhi[r] = uxhi[r]; }
        // keep shfl index < 64: svall covers [svbase, svbase+64)
        if (p0 - svbase >= 32) {
            svbase = p0;
            svall = csr_src[min(svbase + lane, hi - 1)];
        }
    }
}

// ---------------- K6: epilogue (MLP + LN + out-GEMM), 16 nodes/block -------
template<bool F32>
__global__ __launch_bounds__(256) void k_post(
    const void* __restrict__ zs_g, const float* __restrict__ x,
    const float* __restrict__ bias_gat,
    const float* __restrict__ W1, const float* __restrict__ b1,
    const float* __restrict__ gamma, const float* __restrict__ beta,
    const float* __restrict__ W2, const float* __restrict__ b2,
    float* __restrict__ out)
{
    __shared__ float xs[16][64];
    __shared__ float zsh[16][256];
    __shared__ float part[16][4][64];
    __shared__ float redS[16][4], redQ[16][4];

    const int n0 = blockIdx.x * 16;
    const int t = threadIdx.x, lane = t & 63, wv = t >> 6;

    for (int i = t; i < 16 * 64; i += 256) xs[i >> 6][i & 63] = x[n0 * 64 + i];
    __syncthreads();

    float a1[16];
    const float b1v = b1[t];
#pragma unroll
    for (int n = 0; n < 16; n++) a1[n] = b1v;
    for (int k = 0; k < 64; k++) {
        const float w1v = W1[k * 256 + t];
#pragma unroll
        for (int n = 0; n < 16; n++) a1[n] = fmaf(xs[n][k], w1v, a1[n]);
    }

    const float bg = bias_gat[t];
    float z[16];
#pragma unroll
    for (int n = 0; n < 16; n++) {
        const float gv = F32 ? ((const float*)zs_g)[(size_t)(n0 + n) * 256 + t]
                             : bf2f(((const unsigned short*)zs_g)[(size_t)(n0 + n) * 256 + t]);
        z[n] = fast_tanh(a1[n]) + gv + bg;
    }

    const float gm = gamma[t], bt = beta[t];
#pragma unroll
    for (int n = 0; n < 16; n++) {
        float s = z[n], q = z[n] * z[n];
#pragma unroll
        for (int m = 1; m < 64; m <<= 1) { s += __shfl_xor(s, m, 64); q += __shfl_xor(q, m, 64); }
        if (lane == 0) { redS[n][wv] = s; redQ[n][wv] = q; }
    }
    __syncthreads();
#pragma unroll
    for (int n = 0; n < 16; n++) {
        const float s = redS[n][0] + redS[n][1] + redS[n][2] + redS[n][3];
        const float q = redQ[n][0] + redQ[n][1] + redQ[n][2] + redQ[n][3];
        const float mu = s * (1.f / 256.f);
        const float var = q * (1.f / 256.f) - mu * mu;
        const float ivn = rsqrtf(var + LN_EPS);
        zsh[n][t] = (z[n] - mu) * ivn * gm + bt;
    }
    __syncthreads();

    const int j = t & 63, qq = t >> 6;
    float p[16];
#pragma unroll
    for (int n = 0; n < 16; n++) p[n] = 0.f;
    for (int c0 = 0; c0 < 64; c0++) {
        const int c = qq * 64 + c0;
        const float w2v = W2[c * 64 + j];
#pragma unroll
        for (int n = 0; n < 16; n++) p[n] = fmaf(zsh[n][c], w2v, p[n]);
    }
#pragma unroll
    for (int n = 0; n < 16; n++) part[n][qq][j] = p[n];
    __syncthreads();
#pragma unroll
    for (int i = 0; i < 4; i++) {
        const int n = wv * 4 + i;
        const float s = part[n][0][lane] + part[n][1][lane] + part[n][2][lane] + part[n][3][lane];
        out[(size_t)(n0 + n) * 64 + lane] = fast_tanh(s + b2[lane]);
    }
}

// ---------------- launcher --------------------------------------------------
extern "C" void kernel_launch(void* const* d_in, const int* in_sizes, int n_in,
                              void* d_out, int out_size, void* d_ws, size_t ws_size,
                              hipStream_t stream)
{
    const float* x         = (const float*)d_in[0];
    const int*   ei        = (const int*)d_in[1];
    const float* edge_attr = (const float*)d_in[2];
    const float* W_l       = (const float*)d_in[3];
    const float* b_l       = (const float*)d_in[4];
    const float* W_r       = (const float*)d_in[5];
    const float* b_r       = (const float*)d_in[6];
    const float* W_e       = (const float*)d_in[7];
    const float* att       = (const float*)d_in[8];
    const float* bias_gat  = (const float*)d_in[9];
    const float* W1        = (const float*)d_in[10];
    const float* b1        = (const float*)d_in[11];
    const float* gamma     = (const float*)d_in[12];
    const float* beta      = (const float*)d_in[13];
    const float* W2        = (const float*)d_in[14];
    const float* b2        = (const float*)d_in[15];
    float* out = (float*)d_out;

    char* wsb = (char*)d_ws;
    size_t o = 0;
    unsigned short* xl_t   = (unsigned short*)(wsb + o);  o += (size_t)N_NODES * HC * 2;
    unsigned short* xr_t   = (unsigned short*)(wsb + o);  o += (size_t)N_NODES * HC * 2;
    unsigned short* ea_csr = (unsigned short*)(wsb + o);  o += (size_t)N_EDGES * 32 * 2;
    int* csr_src           = (int*)(wsb + o);             o += (size_t)N_EDGES * 4;
    int* count             = (int*)(wsb + o);             o += (size_t)N_NODES * 4;
    int* cursor            = (int*)(wsb + o);             o += (size_t)N_NODES * 4;
    int* off               = (int*)(wsb + o);             o += (size_t)(N_NODES + 1) * 4;
    unsigned short* wfrag  = (unsigned short*)(wsb + o);  o += 16 * 64 * 8 * 2;
    unsigned short* att_t  = (unsigned short*)(wsb + o);  o += 256 * 2;
    o = (o + 255) & ~(size_t)255;
    void* zs_g             = (void*)(wsb + o);
    const bool f32ok = (o + (size_t)N_NODES * HC * 4) <= ws_size;

    hipMemsetAsync(count, 0, 2 * (size_t)N_NODES * sizeof(int), stream);

    k_node_transform<<<N_NODES / 16, 256, 0, stream>>>(x, W_l, b_l, W_r, b_r, xl_t, xr_t);
    k_prep<<<1, 256, 0, stream>>>(W_e, att, wfrag, att_t);
    k_hist<<<(N_EDGES + 255) / 256, 256, 0, stream>>>(ei, count);
    k_scan<<<1, 1024, 0, stream>>>(count, off);
    k_scatter<<<(N_EDGES + 255) / 256, 256, 0, stream>>>(ei, off, cursor, edge_attr,
                                                         csr_src, ea_csr);
    if (f32ok) {
        k_edgeagg<true><<<EDGE_BLOCKS, 256, 0, stream>>>(off, csr_src, ea_csr, wfrag, att_t,
                                                         xl_t, xr_t, zs_g);
        k_post<true><<<N_NODES / 16, 256, 0, stream>>>(zs_g, x, bias_gat,
                                                       W1, b1, gamma, beta, W2, b2, out);
    } else {
        k_edgeagg<false><<<EDGE_BLOCKS, 256, 0, stream>>>(off, csr_src, ea_csr, wfrag, att_t,
                                                          xl_t, xr_t, zs_g);
        k_post<false><<<N_NODES / 16, 256, 0, stream>>>(zs_g, x, bias_gat,
                                                        W1, b1, gamma, beta, W2, b2, out);
    }
}

// Round 18
// 589.951 us; speedup vs baseline: 3.5506x; 1.0139x over previous
//
#include <hip/hip_runtime.h>
#include <math.h>

#define N_NODES 50000
#define N_EDGES 800000
#define HID 64
#define HEADS 4
#define HC 256
#define NEG_SLOPE 0.2f
#define LN_EPS 1e-5f
#define EDGE_BLOCKS 2048   // persistent-wave grid for k_edgeagg (8192 waves)

typedef __attribute__((ext_vector_type(8))) short bf16x8;
typedef __attribute__((ext_vector_type(8))) unsigned short u16x8;
typedef __attribute__((ext_vector_type(4))) float f32x4;

__device__ __forceinline__ float bf2f(unsigned short u) {
    return __uint_as_float(((unsigned int)u) << 16);
}
__device__ __forceinline__ unsigned short f2bf(float f) {
    unsigned int u = __float_as_uint(f);
    u = (u + 0x7fffu + ((u >> 16) & 1u)) >> 16;   // RNE
    return (unsigned short)u;
}
__device__ __forceinline__ float fast_tanh(float v) {
    const float c = fminf(fmaxf(v, -15.f), 15.f);
    const float e = __expf(2.f * c);
    return 1.f - 2.f / (e + 1.f);
}
__device__ __forceinline__ bf16x8 pack_bf8(float4 a, float4 b) {
    u16x8 r;
    r[0] = f2bf(a.x); r[1] = f2bf(a.y); r[2] = f2bf(a.z); r[3] = f2bf(a.w);
    r[4] = f2bf(b.x); r[5] = f2bf(b.y); r[6] = f2bf(b.z); r[7] = f2bf(b.w);
    return __builtin_bit_cast(bf16x8, r);
}

// ---------------- K1: node transform -> TRANSPOSED-TILED bf16 (16 nodes/blk)
__global__ __launch_bounds__(256) void k_node_transform(
    const float* __restrict__ x,
    const float* __restrict__ W_l, const float* __restrict__ b_l,
    const float* __restrict__ W_r, const float* __restrict__ b_r,
    unsigned short* __restrict__ xl_t, unsigned short* __restrict__ xr_t)
{
    __shared__ float xs[16][64];
    __shared__ unsigned short tl[16][256], tr[16][256];
    const int n0 = blockIdx.x * 16;
    const int t = threadIdx.x;
    for (int i = t; i < 16 * 64; i += 256) xs[i >> 6][i & 63] = x[n0 * 64 + i];
    __syncthreads();

    float accl[16], accr[16];
    const float bl = b_l[t], br = b_r[t];
#pragma unroll
    for (int n = 0; n < 16; n++) { accl[n] = bl; accr[n] = br; }
    for (int k = 0; k < 64; k++) {
        const float wl = W_l[k * 256 + t];
        const float wr = W_r[k * 256 + t];
#pragma unroll
        for (int n = 0; n < 16; n++) {
            accl[n] = fmaf(xs[n][k], wl, accl[n]);
            accr[n] = fmaf(xs[n][k], wr, accr[n]);
        }
    }
    const int pos = (t & 15) * 16 + (t >> 4);
#pragma unroll
    for (int n = 0; n < 16; n++) {
        tl[n][pos] = f2bf(accl[n]);
        tr[n][pos] = f2bf(accr[n]);
    }
    __syncthreads();
    const int n = t >> 4, q = t & 15;
#pragma unroll
    for (int i = 0; i < 4; i++) {
        *(ushort4*)(xl_t + (size_t)(n0 + n) * 256 + q * 16 + i * 4) = *(const ushort4*)&tl[n][q * 16 + i * 4];
        *(ushort4*)(xr_t + (size_t)(n0 + n) * 256 + q * 16 + i * 4) = *(const ushort4*)&tr[n][q * 16 + i * 4];
    }
}

// ---------------- K2: histogram of dst ------------------------------------
__global__ __launch_bounds__(256) void k_hist(const int* __restrict__ ei, int* __restrict__ count)
{
    const int e = blockIdx.x * 256 + threadIdx.x;
    if (e < N_EDGES) atomicAdd(&count[ei[N_EDGES + e]], 1);
}

// ---------------- K3: exclusive scan (single block) ------------------------
__global__ __launch_bounds__(1024) void k_scan(const int* __restrict__ count, int* __restrict__ off)
{
    __shared__ int wsum[16];
    __shared__ int s_carry;
    const int t = threadIdx.x, lane = t & 63, wv = t >> 6;
    if (t == 0) s_carry = 0;
    __syncthreads();
    for (int base = 0; base < N_NODES; base += 8192) {
        const int idx0 = base + t * 8;
        int v[8];
#pragma unroll
        for (int j = 0; j < 8; j++) { int i = idx0 + j; v[j] = (i < N_NODES) ? count[i] : 0; }
#pragma unroll
        for (int j = 1; j < 8; j++) v[j] += v[j - 1];
        const int tot = v[7];
        int sc = tot;
#pragma unroll
        for (int s = 1; s < 64; s <<= 1) { int o = __shfl_up(sc, s, 64); if (lane >= s) sc += o; }
        if (lane == 63) wsum[wv] = sc;
        __syncthreads();
        const int carry = s_carry;
        int woff = 0;
        for (int u = 0; u < wv; u++) woff += wsum[u];
        const int ebase = carry + woff + (sc - tot);
#pragma unroll
        for (int j = 0; j < 8; j++) {
            int i = idx0 + j;
            if (i < N_NODES) off[i] = ebase + (j ? v[j - 1] : 0);
        }
        __syncthreads();
        if (t == 0) { int tt = 0; for (int u = 0; u < 16; u++) tt += wsum[u]; s_carry = carry + tt; }
        __syncthreads();
    }
    if (threadIdx.x == 0) off[N_NODES] = s_carry;
}

// ---------------- K4: scatter src + eid into CSR (index-only, 4B) ----------
__global__ __launch_bounds__(256) void k_scatter(
    const int* __restrict__ ei, const int* __restrict__ off, int* __restrict__ cursor,
    int* __restrict__ csr_src, int* __restrict__ eid_csr)
{
    const int e = blockIdx.x * 256 + threadIdx.x;
    if (e < N_EDGES) {
        const int s = ei[e];
        const int d = ei[N_EDGES + e];
        const int pos = off[d] + atomicAdd(&cursor[d], 1);
        csr_src[pos] = s;
        eid_csr[pos] = e;
    }
}

// ---------------- K5: edge+aggregate, persistent waves, deep pipeline ------
// Wave = sequence of nodes. Per-NODE src+eid vectors (svall/evall cover 64
// CSR slots; next node's prefetched a full node ahead). edge_attr gathered
// as raw fp32 rows via eid (no ea_csr materialization) — af prefetched one
// tile ahead covers the random latency; converted to bf16 at rotation.
template<bool F32>
__global__ __launch_bounds__(256) void k_edgeagg(
    const int* __restrict__ off, const int* __restrict__ csr_src,
    const int* __restrict__ eid_csr, const float* __restrict__ edge_attr,
    const float* __restrict__ W_e, const float* __restrict__ att,
    const unsigned short* __restrict__ xl_t, const unsigned short* __restrict__ xr_t,
    void* __restrict__ zs_g)
{
    __shared__ unsigned short bfrag_s[16][64][8];   // 16 KB, only LDS

    const int t = threadIdx.x;
    const int lane = t & 63, wv = t >> 6;
    const int arow = lane & 15, koct = lane >> 4;

    // stage W_e B-frags (fp32 -> bf16 in place of old k_prep)
    for (int i = t; i < 1024; i += 256) {
        const int nt = i >> 6, ls = i & 63;
        const int col = nt * 16 + (ls & 15);
        const int kb = (ls >> 4) * 8;
        unsigned short tmp[8];
#pragma unroll
        for (int j = 0; j < 8; j++) tmp[j] = f2bf(W_e[(kb + j) * 256 + col]);
        *(ushort4*)&bfrag_s[nt][ls][0] = make_ushort4(tmp[0], tmp[1], tmp[2], tmp[3]);
        *(ushort4*)&bfrag_s[nt][ls][4] = make_ushort4(tmp[4], tmp[5], tmp[6], tmp[7]);
    }
    __syncthreads();

    // att in fp32, direct (att_flat[c], c = nt*16+arow)
    float attLf[8], attHf[8];
#pragma unroll
    for (int j = 0; j < 8; j++) {
        attLf[j] = att[j * 16 + arow];
        attHf[j] = att[(j + 8) * 16 + arow];
    }

    const int STRIDE = EDGE_BLOCKS * 4;
    int node = blockIdx.x * 4 + wv;
    if (node >= N_NODES) return;

    // ---- current node context ----
    int lo = off[node], hi = off[node + 1];
    u16x8 xrl = *(const u16x8*)(xr_t + (size_t)node * 256 + arow * 16);
    u16x8 xrh = *(const u16x8*)(xr_t + (size_t)node * 256 + arow * 16 + 8);
    while (hi <= lo) {                    // degree-0 node (rare): zeros, advance
#pragma unroll
        for (int q = 0; q < 4; q++) {
            const int nt = koct * 4 + q;
            if (F32) ((float*)zs_g)[(size_t)node * 256 + nt * 16 + arow] = 0.f;
            else ((unsigned short*)zs_g)[(size_t)node * 256 + nt * 16 + arow] = 0;
        }
        node += STRIDE;
        if (node >= N_NODES) return;
        lo = off[node]; hi = off[node + 1];
        xrl = *(const u16x8*)(xr_t + (size_t)node * 256 + arow * 16);
        xrh = *(const u16x8*)(xr_t + (size_t)node * 256 + arow * 16 + 8);
    }
    int svbase = lo;
    int svall = csr_src[min(svbase + lane, hi - 1)];   // covers 64 CSR slots
    int evall = eid_csr[min(svbase + lane, hi - 1)];

    // ---- prefetch next node context (incl. its src/eid vectors) ----
    int nnode = node + STRIDE;
    bool nvalid = nnode < N_NODES;
    int nlo = 0, nhi = 0, nsvall = 0, nevall = 0;
    u16x8 nxrl = xrl, nxrh = xrh;
    if (nvalid) {
        nlo = off[nnode]; nhi = off[nnode + 1];
        nxrl = *(const u16x8*)(xr_t + (size_t)nnode * 256 + arow * 16);
        nxrh = *(const u16x8*)(xr_t + (size_t)nnode * 256 + arow * 16 + 8);
        if (nhi > nlo) {
            nsvall = csr_src[min(nlo + lane, nhi - 1)];
            nevall = eid_csr[min(nlo + lane, nhi - 1)];
        }
    }
    // ---- first tile chain (cold) ----
    int p0 = lo;
    bf16x8 af;
    u16x8 xlo[4], xhi[4];
    {
        const int eid0 = __shfl(evall, arow, 64);
        const float* ap = edge_attr + (size_t)eid0 * 32 + koct * 8;
        af = pack_bf8(*(const float4*)ap, *(const float4*)(ap + 4));
#pragma unroll
        for (int r = 0; r < 4; r++) {
            const int sr = __shfl(svall, koct * 4 + r, 64);
            const unsigned short* bp = xl_t + (size_t)sr * 256 + arow * 16;
            xlo[r] = *(const u16x8*)bp;
            xhi[r] = *(const u16x8*)(bp + 8);
        }
    }

    float g[16];
#pragma unroll
    for (int i = 0; i < 16; i++) g[i] = 0.f;
    float dsum[4] = {0.f, 0.f, 0.f, 0.f};

    for (;;) {
        const bool last = (p0 + 16 >= hi);
        // ---- identify upcoming tile; issue its af (fp32) load ----
        bool uvalid;
        int up0;
        if (!last) { uvalid = true; up0 = p0 + 16; }
        else {
            while (nvalid && nlo >= nhi) {   // skip empty next nodes (rare)
#pragma unroll
                for (int q = 0; q < 4; q++) {
                    const int nt = koct * 4 + q;
                    if (F32) ((float*)zs_g)[(size_t)nnode * 256 + nt * 16 + arow] = 0.f;
                    else ((unsigned short*)zs_g)[(size_t)nnode * 256 + nt * 16 + arow] = 0;
                }
                nnode += STRIDE;
                nvalid = nnode < N_NODES;
                if (nvalid) {
                    nlo = off[nnode]; nhi = off[nnode + 1];
                    nxrl = *(const u16x8*)(xr_t + (size_t)nnode * 256 + arow * 16);
                    nxrh = *(const u16x8*)(xr_t + (size_t)nnode * 256 + arow * 16 + 8);
                    if (nhi > nlo) {
                        nsvall = csr_src[min(nlo + lane, nhi - 1)];
                        nevall = eid_csr[min(nlo + lane, nhi - 1)];
                    }
                }
            }
            uvalid = nvalid; up0 = nlo;
        }
        float4 uA0 = make_float4(0.f, 0.f, 0.f, 0.f), uA1 = uA0;
        if (uvalid) {
            const int ubase = last ? 0 : (up0 - svbase);
            const int uev = last ? nevall : evall;
            const int ueid = __shfl(uev, ubase + arow, 64);
            const float* ap = edge_attr + (size_t)ueid * 32 + koct * 8;
            uA0 = *(const float4*)ap;
            uA1 = *(const float4*)(ap + 4);
        }

        // ---- compute current tile: nt 0..7 (xlo half), xr folded into C ----
        float s_[4][4];
#pragma unroll
        for (int r = 0; r < 4; r++)
#pragma unroll
            for (int h = 0; h < 4; h++) s_[r][h] = 0.f;

#pragma unroll
        for (int nt = 0; nt < 8; nt++) {
            const bf16x8 bfr = *(const bf16x8*)&bfrag_s[nt][lane][0];
            const float xrv = bf2f((unsigned short)xrl[nt]);
            f32x4 dacc = {xrv, xrv, xrv, xrv};
            dacc = __builtin_amdgcn_mfma_f32_16x16x32_bf16(af, bfr, dacc, 0, 0, 0);
            const float atv = attLf[nt];
            const int h = nt >> 2;
#pragma unroll
            for (int r = 0; r < 4; r++) {
                const float mm = dacc[r] + bf2f((unsigned short)xlo[r][nt]);
                const float lk = fmaxf(mm, NEG_SLOPE * mm);
                s_[r][h] = fmaf(atv, lk, s_[r][h]);
            }
        }
        // ---- mid-tile: shfl in-register src vector, issue upcoming gathers --
        u16x8 uxlo[4], uxhi[4];
        if (uvalid) {
            const int ubase = last ? 0 : (up0 - svbase);
            const int usrcv = last ? nsvall : svall;
#pragma unroll
            for (int r = 0; r < 4; r++) {
                const int sr = __shfl(usrcv, ubase + koct * 4 + r, 64);
                const unsigned short* bp = xl_t + (size_t)sr * 256 + arow * 16;
                uxlo[r] = *(const u16x8*)bp;
                uxhi[r] = *(const u16x8*)(bp + 8);
            }
        } else {
#pragma unroll
            for (int r = 0; r < 4; r++) { uxlo[r] = xlo[r]; uxhi[r] = xhi[r]; }
        }
        // ---- nt 8..15 (xhi half) ----
#pragma unroll
        for (int n2 = 0; n2 < 8; n2++) {
            const int nt = n2 + 8;
            const bf16x8 bfr = *(const bf16x8*)&bfrag_s[nt][lane][0];
            const float xrv = bf2f((unsigned short)xrh[n2]);
            f32x4 dacc = {xrv, xrv, xrv, xrv};
            dacc = __builtin_amdgcn_mfma_f32_16x16x32_bf16(af, bfr, dacc, 0, 0, 0);
            const float atv = attHf[n2];
            const int h = nt >> 2;
#pragma unroll
            for (int r = 0; r < 4; r++) {
                const float mm = dacc[r] + bf2f((unsigned short)xhi[r][n2]);
                const float lk = fmaxf(mm, NEG_SLOPE * mm);
                s_[r][h] = fmaf(atv, lk, s_[r][h]);
            }
        }
        // ---- logit reduce over 16 arow lanes ----
#pragma unroll
        for (int r = 0; r < 4; r++)
#pragma unroll
            for (int h = 0; h < 4; h++) {
                float v = s_[r][h];
                v += __shfl_xor(v, 1, 64);
                v += __shfl_xor(v, 2, 64);
                v += __shfl_xor(v, 4, 64);
                v += __shfl_xor(v, 8, 64);
                s_[r][h] = v;
            }
        // ---- exp + aggregate ----
#pragma unroll
        for (int h = 0; h < 4; h++) {
            float w4[4];
#pragma unroll
            for (int r = 0; r < 4; r++) {
                const bool ok = (p0 + koct * 4 + r) < hi;
                w4[r] = ok ? __expf(fminf(s_[r][h], 60.f)) : 0.f;
            }
            dsum[h] += (w4[0] + w4[1]) + (w4[2] + w4[3]);
#pragma unroll
            for (int q = 0; q < 4; q++) {
                const int nt = h * 4 + q;
                float acc = g[nt];
#pragma unroll
                for (int r = 0; r < 4; r++) {
                    const float xv = bf2f((unsigned short)(nt < 8 ? xlo[r][nt & 7] : xhi[r][nt & 7]));
                    acc = fmaf(w4[r], xv, acc);
                }
                g[nt] = acc;
            }
        }

        // ---- node boundary: reduce + write, rotate node ctx ----
        if (last) {
#pragma unroll
            for (int i = 0; i < 16; i++) {
                float v = g[i];
                v += __shfl_xor(v, 16, 64);
                v += __shfl_xor(v, 32, 64);
                g[i] = v;
            }
#pragma unroll
            for (int h = 0; h < 4; h++) {
                float v = dsum[h];
                v += __shfl_xor(v, 16, 64);
                v += __shfl_xor(v, 32, 64);
                dsum[h] = v;
            }
            float inv[4];
#pragma unroll
            for (int h = 0; h < 4; h++) inv[h] = 1.f / (dsum[h] + 1e-16f);
#pragma unroll
            for (int q = 0; q < 4; q++) {
                const int nt = koct * 4 + q;
                const float v = g[nt] * inv[nt >> 2];
                if (F32) ((float*)zs_g)[(size_t)node * 256 + nt * 16 + arow] = v;
                else ((unsigned short*)zs_g)[(size_t)node * 256 + nt * 16 + arow] = f2bf(v);
            }
            if (!uvalid) return;   // wave done
            node = nnode; lo = nlo; hi = nhi; xrl = nxrl; xrh = nxrh;
            svbase = nlo; svall = nsvall; evall = nevall;
#pragma unroll
            for (int i = 0; i < 16; i++) g[i] = 0.f;
#pragma unroll
            for (int h = 0; h < 4; h++) dsum[h] = 0.f;
            nnode += STRIDE;
            nvalid = nnode < N_NODES;
            if (nvalid) {
                nlo = off[nnode]; nhi = off[nnode + 1];
                nxrl = *(const u16x8*)(xr_t + (size_t)nnode * 256 + arow * 16);
                nxrh = *(const u16x8*)(xr_t + (size_t)nnode * 256 + arow * 16 + 8);
                if (nhi > nlo) {
                    nsvall = csr_src[min(nlo + lane, nhi - 1)];
                    nevall = eid_csr[min(nlo + lane, nhi - 1)];
                }
            }
        }
        // ---- rotate tile state ----
        p0 = up0;
        af = pack_bf8(uA0, uA1);
#pragma unroll
        for (int r = 0; r < 4; r++) { xlo[r] = uxlo[r]; xhi[r] = uxhi[r]; }
        // keep shfl index < 64: svall/evall cover [svbase, svbase+64)
        if (p0 - svbase >= 32) {
            svbase = p0;
            svall = csr_src[min(svbase + lane, hi - 1)];
            evall = eid_csr[min(svbase + lane, hi - 1)];
        }
    }
}

// ---------------- K6: epilogue (MLP + LN + out-GEMM), 16 nodes/block -------
template<bool F32>
__global__ __launch_bounds__(256) void k_post(
    const void* __restrict__ zs_g, const float* __restrict__ x,
    const float* __restrict__ bias_gat,
    const float* __restrict__ W1, const float* __restrict__ b1,
    const float* __restrict__ gamma, const float* __restrict__ beta,
    const float* __restrict__ W2, const float* __restrict__ b2,
    float* __restrict__ out)
{
    __shared__ float xs[16][64];
    __shared__ float zsh[16][256];
    __shared__ float part[16][4][64];
    __shared__ float redS[16][4], redQ[16][4];

    const int n0 = blockIdx.x * 16;
    const int t = threadIdx.x, lane = t & 63, wv = t >> 6;

    for (int i = t; i < 16 * 64; i += 256) xs[i >> 6][i & 63] = x[n0 * 64 + i];
    __syncthreads();

    float a1[16];
    const float b1v = b1[t];
#pragma unroll
    for (int n = 0; n < 16; n++) a1[n] = b1v;
    for (int k = 0; k < 64; k++) {
        const float w1v = W1[k * 256 + t];
#pragma unroll
        for (int n = 0; n < 16; n++) a1[n] = fmaf(xs[n][k], w1v, a1[n]);
    }

    const float bg = bias_gat[t];
    float z[16];
#pragma unroll
    for (int n = 0; n < 16; n++) {
        const float gv = F32 ? ((const float*)zs_g)[(size_t)(n0 + n) * 256 + t]
                             : bf2f(((const unsigned short*)zs_g)[(size_t)(n0 + n) * 256 + t]);
        z[n] = fast_tanh(a1[n]) + gv + bg;
    }

    const float gm = gamma[t], bt = beta[t];
#pragma unroll
    for (int n = 0; n < 16; n++) {
        float s = z[n], q = z[n] * z[n];
#pragma unroll
        for (int m = 1; m < 64; m <<= 1) { s += __shfl_xor(s, m, 64); q += __shfl_xor(q, m, 64); }
        if (lane == 0) { redS[n][wv] = s; redQ[n][wv] = q; }
    }
    __syncthreads();
#pragma unroll
    for (int n = 0; n < 16; n++) {
        const float s = redS[n][0] + redS[n][1] + redS[n][2] + redS[n][3];
        const float q = redQ[n][0] + redQ[n][1] + redQ[n][2] + redQ[n][3];
        const float mu = s * (1.f / 256.f);
        const float var = q * (1.f / 256.f) - mu * mu;
        const float ivn = rsqrtf(var + LN_EPS);
        zsh[n][t] = (z[n] - mu) * ivn * gm + bt;
    }
    __syncthreads();

    const int j = t & 63, qq = t >> 6;
    float p[16];
#pragma unroll
    for (int n = 0; n < 16; n++) p[n] = 0.f;
    for (int c0 = 0; c0 < 64; c0++) {
        const int c = qq * 64 + c0;
        const float w2v = W2[c * 64 + j];
#pragma unroll
        for (int n = 0; n < 16; n++) p[n] = fmaf(zsh[n][c], w2v, p[n]);
    }
#pragma unroll
    for (int n = 0; n < 16; n++) part[n][qq][j] = p[n];
    __syncthreads();
#pragma unroll
    for (int i = 0; i < 4; i++) {
        const int n = wv * 4 + i;
        const float s = part[n][0][lane] + part[n][1][lane] + part[n][2][lane] + part[n][3][lane];
        out[(size_t)(n0 + n) * 64 + lane] = fast_tanh(s + b2[lane]);
    }
}

// ---------------- launcher --------------------------------------------------
extern "C" void kernel_launch(void* const* d_in, const int* in_sizes, int n_in,
                              void* d_out, int out_size, void* d_ws, size_t ws_size,
                              hipStream_t stream)
{
    const float* x         = (const float*)d_in[0];
    const int*   ei        = (const int*)d_in[1];
    const float* edge_attr = (const float*)d_in[2];
    const float* W_l       = (const float*)d_in[3];
    const float* b_l       = (const float*)d_in[4];
    const float* W_r       = (const float*)d_in[5];
    const float* b_r       = (const float*)d_in[6];
    const float* W_e       = (const float*)d_in[7];
    const float* att       = (const float*)d_in[8];
    const float* bias_gat  = (const float*)d_in[9];
    const float* W1        = (const float*)d_in[10];
    const float* b1        = (const float*)d_in[11];
    const float* gamma     = (const float*)d_in[12];
    const float* beta      = (const float*)d_in[13];
    const float* W2        = (const float*)d_in[14];
    const float* b2        = (const float*)d_in[15];
    float* out = (float*)d_out;

    char* wsb = (char*)d_ws;
    size_t o = 0;
    unsigned short* xl_t   = (unsigned short*)(wsb + o);  o += (size_t)N_NODES * HC * 2;
    unsigned short* xr_t   = (unsigned short*)(wsb + o);  o += (size_t)N_NODES * HC * 2;
    int* csr_src           = (int*)(wsb + o);             o += (size_t)N_EDGES * 4;
    int* eid_csr           = (int*)(wsb + o);             o += (size_t)N_EDGES * 4;
    int* count             = (int*)(wsb + o);             o += (size_t)N_NODES * 4;
    int* cursor            = (int*)(wsb + o);             o += (size_t)N_NODES * 4;
    int* off               = (int*)(wsb + o);             o += (size_t)(N_NODES + 1) * 4;
    o = (o + 255) & ~(size_t)255;
    void* zs_g             = (void*)(wsb + o);
    const bool f32ok = (o + (size_t)N_NODES * HC * 4) <= ws_size;

    hipMemsetAsync(count, 0, 2 * (size_t)N_NODES * sizeof(int), stream);

    k_node_transform<<<N_NODES / 16, 256, 0, stream>>>(x, W_l, b_l, W_r, b_r, xl_t, xr_t);
    k_hist<<<(N_EDGES + 255) / 256, 256, 0, stream>>>(ei, count);
    k_scan<<<1, 1024, 0, stream>>>(count, off);
    k_scatter<<<(N_EDGES + 255) / 256, 256, 0, stream>>>(ei, off, cursor, csr_src, eid_csr);
    if (f32ok) {
        k_edgeagg<true><<<EDGE_BLOCKS, 256, 0, stream>>>(off, csr_src, eid_csr, edge_attr,
                                                         W_e, att, xl_t, xr_t, zs_g);
        k_post<true><<<N_NODES / 16, 256, 0, stream>>>(zs_g, x, bias_gat,
                                                       W1, b1, gamma, beta, W2, b2, out);
    } else {
        k_edgeagg<false><<<EDGE_BLOCKS, 256, 0, stream>>>(off, csr_src, eid_csr, edge_attr,
                                                          W_e, att, xl_t, xr_t, zs_g);
        k_post<false><<<N_NODES / 16, 256, 0, stream>>>(zs_g, x, bias_gat,
                                                        W1, b1, gamma, beta, W2, b2, out);
    }
}

// Round 19
// 560.792 us; speedup vs baseline: 3.7353x; 1.0520x over previous
//
#include <hip/hip_runtime.h>
#include <math.h>

#define N_NODES 50000
#define N_EDGES 800000
#define HID 64
#define HEADS 4
#define HC 256
#define NEG_SLOPE 0.2f
#define LN_EPS 1e-5f
#define EDGE_BLOCKS 2048   // persistent-wave grid for k_edgeagg (8192 waves)

typedef __attribute__((ext_vector_type(8))) short bf16x8;
typedef __attribute__((ext_vector_type(8))) unsigned short u16x8;
typedef __attribute__((ext_vector_type(4))) float f32x4;

__device__ __forceinline__ float bf2f(unsigned short u) {
    return __uint_as_float(((unsigned int)u) << 16);
}
__device__ __forceinline__ unsigned short f2bf(float f) {
    unsigned int u = __float_as_uint(f);
    u = (u + 0x7fffu + ((u >> 16) & 1u)) >> 16;   // RNE
    return (unsigned short)u;
}
__device__ __forceinline__ float fast_tanh(float v) {
    const float c = fminf(fmaxf(v, -15.f), 15.f);
    const float e = __expf(2.f * c);
    return 1.f - 2.f / (e + 1.f);
}
__device__ __forceinline__ bf16x8 pack_bf8(float4 a, float4 b) {
    u16x8 r;
    r[0] = f2bf(a.x); r[1] = f2bf(a.y); r[2] = f2bf(a.z); r[3] = f2bf(a.w);
    r[4] = f2bf(b.x); r[5] = f2bf(b.y); r[6] = f2bf(b.z); r[7] = f2bf(b.w);
    return __builtin_bit_cast(bf16x8, r);
}

// ---------------- K1: MFMA node transform (64 nodes/block, 4 waves) --------
// Wave = 16 nodes. A: x rows (fp32->bf16), B: W_l/W_r frags in LDS, bias in
// C-operand. D(row=koct*4+r, col=nt*16+arow) packed to transposed-tiled
// xl_t/xr_t[node][arow*16+nt] as 2x16B contiguous writes.
__global__ __launch_bounds__(256) void k_ntm(
    const float* __restrict__ x,
    const float* __restrict__ W_l, const float* __restrict__ b_l,
    const float* __restrict__ W_r, const float* __restrict__ b_r,
    unsigned short* __restrict__ xl_t, unsigned short* __restrict__ xr_t)
{
    __shared__ unsigned short wl_s[2][16][64][8];   // 32 KB
    __shared__ unsigned short wr_s[2][16][64][8];   // 32 KB
    const int t = threadIdx.x, lane = t & 63, wv = t >> 6;
    const int arow = lane & 15, koct = lane >> 4;

    for (int i = t; i < 2048; i += 256) {
        const int ks = i >> 10, nt = (i >> 6) & 15, ls = i & 63;
        const int col = nt * 16 + (ls & 15);
        const int kb = ks * 32 + (ls >> 4) * 8;
        unsigned short a[8], b[8];
#pragma unroll
        for (int j = 0; j < 8; j++) {
            a[j] = f2bf(W_l[(kb + j) * 256 + col]);
            b[j] = f2bf(W_r[(kb + j) * 256 + col]);
        }
        *(ushort4*)&wl_s[ks][nt][ls][0] = make_ushort4(a[0], a[1], a[2], a[3]);
        *(ushort4*)&wl_s[ks][nt][ls][4] = make_ushort4(a[4], a[5], a[6], a[7]);
        *(ushort4*)&wr_s[ks][nt][ls][0] = make_ushort4(b[0], b[1], b[2], b[3]);
        *(ushort4*)&wr_s[ks][nt][ls][4] = make_ushort4(b[4], b[5], b[6], b[7]);
    }
    __syncthreads();

    const int n0w = blockIdx.x * 64 + wv * 16;
    if (n0w >= N_NODES) return;

    // A-frags: x row (n0w+arow), k = ks*32 + koct*8 + j
    const float* xrow = x + (size_t)(n0w + arow) * 64;
    const bf16x8 af0 = pack_bf8(*(const float4*)(xrow + koct * 8),
                                *(const float4*)(xrow + koct * 8 + 4));
    const bf16x8 af1 = pack_bf8(*(const float4*)(xrow + 32 + koct * 8),
                                *(const float4*)(xrow + 32 + koct * 8 + 4));

    // ---- W_l pass ----
    float acc[4][16];
#pragma unroll
    for (int nt = 0; nt < 16; nt++) {
        const float bv = b_l[nt * 16 + arow];
        f32x4 d = {bv, bv, bv, bv};
        d = __builtin_amdgcn_mfma_f32_16x16x32_bf16(af0, *(const bf16x8*)&wl_s[0][nt][lane][0], d, 0, 0, 0);
        d = __builtin_amdgcn_mfma_f32_16x16x32_bf16(af1, *(const bf16x8*)&wl_s[1][nt][lane][0], d, 0, 0, 0);
#pragma unroll
        for (int r = 0; r < 4; r++) acc[r][nt] = d[r];
    }
#pragma unroll
    for (int r = 0; r < 4; r++) {
        u16x8 lo, hi;
#pragma unroll
        for (int j = 0; j < 8; j++) { lo[j] = f2bf(acc[r][j]); hi[j] = f2bf(acc[r][j + 8]); }
        unsigned short* dst = xl_t + (size_t)(n0w + koct * 4 + r) * 256 + arow * 16;
        *(u16x8*)dst = lo;
        *(u16x8*)(dst + 8) = hi;
    }
    // ---- W_r pass ----
#pragma unroll
    for (int nt = 0; nt < 16; nt++) {
        const float bv = b_r[nt * 16 + arow];
        f32x4 d = {bv, bv, bv, bv};
        d = __builtin_amdgcn_mfma_f32_16x16x32_bf16(af0, *(const bf16x8*)&wr_s[0][nt][lane][0], d, 0, 0, 0);
        d = __builtin_amdgcn_mfma_f32_16x16x32_bf16(af1, *(const bf16x8*)&wr_s[1][nt][lane][0], d, 0, 0, 0);
#pragma unroll
        for (int r = 0; r < 4; r++) acc[r][nt] = d[r];
    }
#pragma unroll
    for (int r = 0; r < 4; r++) {
        u16x8 lo, hi;
#pragma unroll
        for (int j = 0; j < 8; j++) { lo[j] = f2bf(acc[r][j]); hi[j] = f2bf(acc[r][j + 8]); }
        unsigned short* dst = xr_t + (size_t)(n0w + koct * 4 + r) * 256 + arow * 16;
        *(u16x8*)dst = lo;
        *(u16x8*)(dst + 8) = hi;
    }
}

// ---------------- K1b: permute channel-indexed weights to pos-space --------
// pos(c) = (c&15)*16 + (c>>4). Lets k_post consume pos-major z_t with its
// original coalesced structure.
__global__ __launch_bounds__(256) void k_permw(
    const float* __restrict__ W1, const float* __restrict__ b1,
    const float* __restrict__ gamma, const float* __restrict__ beta,
    const float* __restrict__ bias_gat, const float* __restrict__ W2,
    float* __restrict__ W1p, float* __restrict__ b1p,
    float* __restrict__ gammap, float* __restrict__ betap,
    float* __restrict__ biasgp, float* __restrict__ W2p)
{
    const int c = threadIdx.x;
    const int pos = (c & 15) * 16 + (c >> 4);
    for (int k = 0; k < 64; k++) W1p[k * 256 + pos] = W1[k * 256 + c];
    b1p[pos] = b1[c];
    gammap[pos] = gamma[c];
    betap[pos] = beta[c];
    biasgp[pos] = bias_gat[c];
    for (int j = 0; j < 64; j++) W2p[pos * 64 + j] = W2[c * 64 + j];
}

// ---------------- K2: histogram of dst ------------------------------------
__global__ __launch_bounds__(256) void k_hist(const int* __restrict__ ei, int* __restrict__ count)
{
    const int e = blockIdx.x * 256 + threadIdx.x;
    if (e < N_EDGES) atomicAdd(&count[ei[N_EDGES + e]], 1);
}

// ---------------- K3: exclusive scan (single block) ------------------------
__global__ __launch_bounds__(1024) void k_scan(const int* __restrict__ count, int* __restrict__ off)
{
    __shared__ int wsum[16];
    __shared__ int s_carry;
    const int t = threadIdx.x, lane = t & 63, wv = t >> 6;
    if (t == 0) s_carry = 0;
    __syncthreads();
    for (int base = 0; base < N_NODES; base += 8192) {
        const int idx0 = base + t * 8;
        int v[8];
#pragma unroll
        for (int j = 0; j < 8; j++) { int i = idx0 + j; v[j] = (i < N_NODES) ? count[i] : 0; }
#pragma unroll
        for (int j = 1; j < 8; j++) v[j] += v[j - 1];
        const int tot = v[7];
        int sc = tot;
#pragma unroll
        for (int s = 1; s < 64; s <<= 1) { int o = __shfl_up(sc, s, 64); if (lane >= s) sc += o; }
        if (lane == 63) wsum[wv] = sc;
        __syncthreads();
        const int carry = s_carry;
        int woff = 0;
        for (int u = 0; u < wv; u++) woff += wsum[u];
        const int ebase = carry + woff + (sc - tot);
#pragma unroll
        for (int j = 0; j < 8; j++) {
            int i = idx0 + j;
            if (i < N_NODES) off[i] = ebase + (j ? v[j - 1] : 0);
        }
        __syncthreads();
        if (t == 0) { int tt = 0; for (int u = 0; u < 16; u++) tt += wsum[u]; s_carry = carry + tt; }
        __syncthreads();
    }
    if (threadIdx.x == 0) off[N_NODES] = s_carry;
}

// ---------------- K4: scatter src + eid into CSR (index-only, 4B) ----------
__global__ __launch_bounds__(256) void k_scatter(
    const int* __restrict__ ei, const int* __restrict__ off, int* __restrict__ cursor,
    int* __restrict__ csr_src, int* __restrict__ eid_csr)
{
    const int e = blockIdx.x * 256 + threadIdx.x;
    if (e < N_EDGES) {
        const int s = ei[e];
        const int d = ei[N_EDGES + e];
        const int pos = off[d] + atomicAdd(&cursor[d], 1);
        csr_src[pos] = s;
        eid_csr[pos] = e;
    }
}

// ---------------- K5: edge+aggregate, persistent waves, deep pipeline ------
// Normalized g written POS-MAJOR: one float4 (or ushort4) per lane at
// z_t[node*256 + arow*16 + koct*4].
template<bool F32>
__global__ __launch_bounds__(256) void k_edgeagg(
    const int* __restrict__ off, const int* __restrict__ csr_src,
    const int* __restrict__ eid_csr, const float* __restrict__ edge_attr,
    const float* __restrict__ W_e, const float* __restrict__ att,
    const unsigned short* __restrict__ xl_t, const unsigned short* __restrict__ xr_t,
    void* __restrict__ zs_g)
{
    __shared__ unsigned short bfrag_s[16][64][8];   // 16 KB, only LDS

    const int t = threadIdx.x;
    const int lane = t & 63, wv = t >> 6;
    const int arow = lane & 15, koct = lane >> 4;

    for (int i = t; i < 1024; i += 256) {
        const int nt = i >> 6, ls = i & 63;
        const int col = nt * 16 + (ls & 15);
        const int kb = (ls >> 4) * 8;
        unsigned short tmp[8];
#pragma unroll
        for (int j = 0; j < 8; j++) tmp[j] = f2bf(W_e[(kb + j) * 256 + col]);
        *(ushort4*)&bfrag_s[nt][ls][0] = make_ushort4(tmp[0], tmp[1], tmp[2], tmp[3]);
        *(ushort4*)&bfrag_s[nt][ls][4] = make_ushort4(tmp[4], tmp[5], tmp[6], tmp[7]);
    }
    __syncthreads();

    float attLf[8], attHf[8];
#pragma unroll
    for (int j = 0; j < 8; j++) {
        attLf[j] = att[j * 16 + arow];
        attHf[j] = att[(j + 8) * 16 + arow];
    }

    const int STRIDE = EDGE_BLOCKS * 4;
    int node = blockIdx.x * 4 + wv;
    if (node >= N_NODES) return;

    int lo = off[node], hi = off[node + 1];
    u16x8 xrl = *(const u16x8*)(xr_t + (size_t)node * 256 + arow * 16);
    u16x8 xrh = *(const u16x8*)(xr_t + (size_t)node * 256 + arow * 16 + 8);
    while (hi <= lo) {
        if (F32) *(float4*)((float*)zs_g + (size_t)node * 256 + arow * 16 + koct * 4) = make_float4(0.f, 0.f, 0.f, 0.f);
        else *(ushort4*)((unsigned short*)zs_g + (size_t)node * 256 + arow * 16 + koct * 4) = make_ushort4(0, 0, 0, 0);
        node += STRIDE;
        if (node >= N_NODES) return;
        lo = off[node]; hi = off[node + 1];
        xrl = *(const u16x8*)(xr_t + (size_t)node * 256 + arow * 16);
        xrh = *(const u16x8*)(xr_t + (size_t)node * 256 + arow * 16 + 8);
    }
    int svbase = lo;
    int svall = csr_src[min(svbase + lane, hi - 1)];
    int evall = eid_csr[min(svbase + lane, hi - 1)];

    int nnode = node + STRIDE;
    bool nvalid = nnode < N_NODES;
    int nlo = 0, nhi = 0, nsvall = 0, nevall = 0;
    u16x8 nxrl = xrl, nxrh = xrh;
    if (nvalid) {
        nlo = off[nnode]; nhi = off[nnode + 1];
        nxrl = *(const u16x8*)(xr_t + (size_t)nnode * 256 + arow * 16);
        nxrh = *(const u16x8*)(xr_t + (size_t)nnode * 256 + arow * 16 + 8);
        if (nhi > nlo) {
            nsvall = csr_src[min(nlo + lane, nhi - 1)];
            nevall = eid_csr[min(nlo + lane, nhi - 1)];
        }
    }
    int p0 = lo;
    bf16x8 af;
    u16x8 xlo[4], xhi[4];
    {
        const int eid0 = __shfl(evall, arow, 64);
        const float* ap = edge_attr + (size_t)eid0 * 32 + koct * 8;
        af = pack_bf8(*(const float4*)ap, *(const float4*)(ap + 4));
#pragma unroll
        for (int r = 0; r < 4; r++) {
            const int sr = __shfl(svall, koct * 4 + r, 64);
            const unsigned short* bp = xl_t + (size_t)sr * 256 + arow * 16;
            xlo[r] = *(const u16x8*)bp;
            xhi[r] = *(const u16x8*)(bp + 8);
        }
    }

    float g[16];
#pragma unroll
    for (int i = 0; i < 16; i++) g[i] = 0.f;
    float dsum[4] = {0.f, 0.f, 0.f, 0.f};

    for (;;) {
        const bool last = (p0 + 16 >= hi);
        bool uvalid;
        int up0;
        if (!last) { uvalid = true; up0 = p0 + 16; }
        else {
            while (nvalid && nlo >= nhi) {
                if (F32) *(float4*)((float*)zs_g + (size_t)nnode * 256 + arow * 16 + koct * 4) = make_float4(0.f, 0.f, 0.f, 0.f);
                else *(ushort4*)((unsigned short*)zs_g + (size_t)nnode * 256 + arow * 16 + koct * 4) = make_ushort4(0, 0, 0, 0);
                nnode += STRIDE;
                nvalid = nnode < N_NODES;
                if (nvalid) {
                    nlo = off[nnode]; nhi = off[nnode + 1];
                    nxrl = *(const u16x8*)(xr_t + (size_t)nnode * 256 + arow * 16);
                    nxrh = *(const u16x8*)(xr_t + (size_t)nnode * 256 + arow * 16 + 8);
                    if (nhi > nlo) {
                        nsvall = csr_src[min(nlo + lane, nhi - 1)];
                        nevall = eid_csr[min(nlo + lane, nhi - 1)];
                    }
                }
            }
            uvalid = nvalid; up0 = nlo;
        }
        float4 uA0 = make_float4(0.f, 0.f, 0.f, 0.f), uA1 = uA0;
        if (uvalid) {
            const int ubase = last ? 0 : (up0 - svbase);
            const int uev = last ? nevall : evall;
            const int ueid = __shfl(uev, ubase + arow, 64);
            const float* ap = edge_attr + (size_t)ueid * 32 + koct * 8;
            uA0 = *(const float4*)ap;
            uA1 = *(const float4*)(ap + 4);
        }

        float s_[4][4];
#pragma unroll
        for (int r = 0; r < 4; r++)
#pragma unroll
            for (int h = 0; h < 4; h++) s_[r][h] = 0.f;

#pragma unroll
        for (int nt = 0; nt < 8; nt++) {
            const bf16x8 bfr = *(const bf16x8*)&bfrag_s[nt][lane][0];
            const float xrv = bf2f((unsigned short)xrl[nt]);
            f32x4 dacc = {xrv, xrv, xrv, xrv};
            dacc = __builtin_amdgcn_mfma_f32_16x16x32_bf16(af, bfr, dacc, 0, 0, 0);
            const float atv = attLf[nt];
            const int h = nt >> 2;
#pragma unroll
            for (int r = 0; r < 4; r++) {
                const float mm = dacc[r] + bf2f((unsigned short)xlo[r][nt]);
                const float lk = fmaxf(mm, NEG_SLOPE * mm);
                s_[r][h] = fmaf(atv, lk, s_[r][h]);
            }
        }
        u16x8 uxlo[4], uxhi[4];
        if (uvalid) {
            const int ubase = last ? 0 : (up0 - svbase);
            const int usrcv = last ? nsvall : svall;
#pragma unroll
            for (int r = 0; r < 4; r++) {
                const int sr = __shfl(usrcv, ubase + koct * 4 + r, 64);
                const unsigned short* bp = xl_t + (size_t)sr * 256 + arow * 16;
                uxlo[r] = *(const u16x8*)bp;
                uxhi[r] = *(const u16x8*)(bp + 8);
            }
        } else {
#pragma unroll
            for (int r = 0; r < 4; r++) { uxlo[r] = xlo[r]; uxhi[r] = xhi[r]; }
        }
#pragma unroll
        for (int n2 = 0; n2 < 8; n2++) {
            const int nt = n2 + 8;
            const bf16x8 bfr = *(const bf16x8*)&bfrag_s[nt][lane][0];
            const float xrv = bf2f((unsigned short)xrh[n2]);
            f32x4 dacc = {xrv, xrv, xrv, xrv};
            dacc = __builtin_amdgcn_mfma_f32_16x16x32_bf16(af, bfr, dacc, 0, 0, 0);
            const float atv = attHf[n2];
            const int h = nt >> 2;
#pragma unroll
            for (int r = 0; r < 4; r++) {
                const float mm = dacc[r] + bf2f((unsigned short)xhi[r][n2]);
                const float lk = fmaxf(mm, NEG_SLOPE * mm);
                s_[r][h] = fmaf(atv, lk, s_[r][h]);
            }
        }
#pragma unroll
        for (int r = 0; r < 4; r++)
#pragma unroll
            for (int h = 0; h < 4; h++) {
                float v = s_[r][h];
                v += __shfl_xor(v, 1, 64);
                v += __shfl_xor(v, 2, 64);
                v += __shfl_xor(v, 4, 64);
                v += __shfl_xor(v, 8, 64);
                s_[r][h] = v;
            }
#pragma unroll
        for (int h = 0; h < 4; h++) {
            float w4[4];
#pragma unroll
            for (int r = 0; r < 4; r++) {
                const bool ok = (p0 + koct * 4 + r) < hi;
                w4[r] = ok ? __expf(fminf(s_[r][h], 60.f)) : 0.f;
            }
            dsum[h] += (w4[0] + w4[1]) + (w4[2] + w4[3]);
#pragma unroll
            for (int q = 0; q < 4; q++) {
                const int nt = h * 4 + q;
                float acc = g[nt];
#pragma unroll
                for (int r = 0; r < 4; r++) {
                    const float xv = bf2f((unsigned short)(nt < 8 ? xlo[r][nt & 7] : xhi[r][nt & 7]));
                    acc = fmaf(w4[r], xv, acc);
                }
                g[nt] = acc;
            }
        }

        if (last) {
#pragma unroll
            for (int i = 0; i < 16; i++) {
                float v = g[i];
                v += __shfl_xor(v, 16, 64);
                v += __shfl_xor(v, 32, 64);
                g[i] = v;
            }
#pragma unroll
            for (int h = 0; h < 4; h++) {
                float v = dsum[h];
                v += __shfl_xor(v, 16, 64);
                v += __shfl_xor(v, 32, 64);
                dsum[h] = v;
            }
            const float inv = 1.f / (dsum[koct] + 1e-16f);
            if (F32) {
                *(float4*)((float*)zs_g + (size_t)node * 256 + arow * 16 + koct * 4) =
                    make_float4(g[koct * 4] * inv, g[koct * 4 + 1] * inv,
                                g[koct * 4 + 2] * inv, g[koct * 4 + 3] * inv);
            } else {
                *(ushort4*)((unsigned short*)zs_g + (size_t)node * 256 + arow * 16 + koct * 4) =
                    make_ushort4(f2bf(g[koct * 4] * inv), f2bf(g[koct * 4 + 1] * inv),
                                 f2bf(g[koct * 4 + 2] * inv), f2bf(g[koct * 4 + 3] * inv));
            }
            if (!uvalid) return;
            node = nnode; lo = nlo; hi = nhi; xrl = nxrl; xrh = nxrh;
            svbase = nlo; svall = nsvall; evall = nevall;
#pragma unroll
            for (int i = 0; i < 16; i++) g[i] = 0.f;
#pragma unroll
            for (int h = 0; h < 4; h++) dsum[h] = 0.f;
            nnode += STRIDE;
            nvalid = nnode < N_NODES;
            if (nvalid) {
                nlo = off[nnode]; nhi = off[nnode + 1];
                nxrl = *(const u16x8*)(xr_t + (size_t)nnode * 256 + arow * 16);
                nxrh = *(const u16x8*)(xr_t + (size_t)nnode * 256 + arow * 16 + 8);
                if (nhi > nlo) {
                    nsvall = csr_src[min(nlo + lane, nhi - 1)];
                    nevall = eid_csr[min(nlo + lane, nhi - 1)];
                }
            }
        }
        p0 = up0;
        af = pack_bf8(uA0, uA1);
#pragma unroll
        for (int r = 0; r < 4; r++) { xlo[r] = uxlo[r]; xhi[r] = uxhi[r]; }
        if (p0 - svbase >= 32) {
            svbase = p0;
            svall = csr_src[min(svbase + lane, hi - 1)];
            evall = eid_csr[min(svbase + lane, hi - 1)];
        }
    }
}

// ---------------- K6: epilogue (MLP + LN + out-GEMM), 16 nodes/block -------
// Operates in pos-space via permuted weights; z_t reads stay coalesced.
template<bool F32>
__global__ __launch_bounds__(256) void k_post(
    const void* __restrict__ zs_g, const float* __restrict__ x,
    const float* __restrict__ biasgp,
    const float* __restrict__ W1p, const float* __restrict__ b1p,
    const float* __restrict__ gammap, const float* __restrict__ betap,
    const float* __restrict__ W2p, const float* __restrict__ b2,
    float* __restrict__ out)
{
    __shared__ float xs[16][64];
    __shared__ float zsh[16][256];
    __shared__ float part[16][4][64];
    __shared__ float redS[16][4], redQ[16][4];

    const int n0 = blockIdx.x * 16;
    const int t = threadIdx.x, lane = t & 63, wv = t >> 6;

    for (int i = t; i < 16 * 64; i += 256) xs[i >> 6][i & 63] = x[n0 * 64 + i];
    __syncthreads();

    float a1[16];
    const float b1v = b1p[t];
#pragma unroll
    for (int n = 0; n < 16; n++) a1[n] = b1v;
    for (int k = 0; k < 64; k++) {
        const float w1v = W1p[k * 256 + t];
#pragma unroll
        for (int n = 0; n < 16; n++) a1[n] = fmaf(xs[n][k], w1v, a1[n]);
    }

    const float bg = biasgp[t];
    float z[16];
#pragma unroll
    for (int n = 0; n < 16; n++) {
        const float gv = F32 ? ((const float*)zs_g)[(size_t)(n0 + n) * 256 + t]
                             : bf2f(((const unsigned short*)zs_g)[(size_t)(n0 + n) * 256 + t]);
        z[n] = fast_tanh(a1[n]) + gv + bg;
    }

    const float gm = gammap[t], bt = betap[t];
#pragma unroll
    for (int n = 0; n < 16; n++) {
        float s = z[n], q = z[n] * z[n];
#pragma unroll
        for (int m = 1; m < 64; m <<= 1) { s += __shfl_xor(s, m, 64); q += __shfl_xor(q, m, 64); }
        if (lane == 0) { redS[n][wv] = s; redQ[n][wv] = q; }
    }
    __syncthreads();
#pragma unroll
    for (int n = 0; n < 16; n++) {
        const float s = redS[n][0] + redS[n][1] + redS[n][2] + redS[n][3];
        const float q = redQ[n][0] + redQ[n][1] + redQ[n][2] + redQ[n][3];
        const float mu = s * (1.f / 256.f);
        const float var = q * (1.f / 256.f) - mu * mu;
        const float ivn = rsqrtf(var + LN_EPS);
        zsh[n][t] = (z[n] - mu) * ivn * gm + bt;
    }
    __syncthreads();

    const int j = t & 63, qq = t >> 6;
    float p[16];
#pragma unroll
    for (int n = 0; n < 16; n++) p[n] = 0.f;
    for (int c0 = 0; c0 < 64; c0++) {
        const int c = qq * 64 + c0;
        const float w2v = W2p[c * 64 + j];
#pragma unroll
        for (int n = 0; n < 16; n++) p[n] = fmaf(zsh[n][c], w2v, p[n]);
    }
#pragma unroll
    for (int n = 0; n < 16; n++) part[n][qq][j] = p[n];
    __syncthreads();
#pragma unroll
    for (int i = 0; i < 4; i++) {
        const int n = wv * 4 + i;
        const float s = part[n][0][lane] + part[n][1][lane] + part[n][2][lane] + part[n][3][lane];
        out[(size_t)(n0 + n) * 64 + lane] = fast_tanh(s + b2[lane]);
    }
}

// ---------------- launcher --------------------------------------------------
extern "C" void kernel_launch(void* const* d_in, const int* in_sizes, int n_in,
                              void* d_out, int out_size, void* d_ws, size_t ws_size,
                              hipStream_t stream)
{
    const float* x         = (const float*)d_in[0];
    const int*   ei        = (const int*)d_in[1];
    const float* edge_attr = (const float*)d_in[2];
    const float* W_l       = (const float*)d_in[3];
    const float* b_l       = (const float*)d_in[4];
    const float* W_r       = (const float*)d_in[5];
    const float* b_r       = (const float*)d_in[6];
    const float* W_e       = (const float*)d_in[7];
    const float* att       = (const float*)d_in[8];
    const float* bias_gat  = (const float*)d_in[9];
    const float* W1        = (const float*)d_in[10];
    const float* b1        = (const float*)d_in[11];
    const float* gamma     = (const float*)d_in[12];
    const float* beta      = (const float*)d_in[13];
    const float* W2        = (const float*)d_in[14];
    const float* b2        = (const float*)d_in[15];
    float* out = (float*)d_out;

    char* wsb = (char*)d_ws;
    size_t o = 0;
    unsigned short* xl_t   = (unsigned short*)(wsb + o);  o += (size_t)N_NODES * HC * 2;
    unsigned short* xr_t   = (unsigned short*)(wsb + o);  o += (size_t)N_NODES * HC * 2;
    int* csr_src           = (int*)(wsb + o);             o += (size_t)N_EDGES * 4;
    int* eid_csr           = (int*)(wsb + o);             o += (size_t)N_EDGES * 4;
    int* count             = (int*)(wsb + o);             o += (size_t)N_NODES * 4;
    int* cursor            = (int*)(wsb + o);             o += (size_t)N_NODES * 4;
    int* off               = (int*)(wsb + o);             o += (size_t)(N_NODES + 1) * 4;
    float* W1p             = (float*)(wsb + o);           o += 64 * 256 * 4;
    float* W2p             = (float*)(wsb + o);           o += 256 * 64 * 4;
    float* b1p             = (float*)(wsb + o);           o += 256 * 4;
    float* gammap          = (float*)(wsb + o);           o += 256 * 4;
    float* betap           = (float*)(wsb + o);           o += 256 * 4;
    float* biasgp          = (float*)(wsb + o);           o += 256 * 4;
    o = (o + 255) & ~(size_t)255;
    void* zs_g             = (void*)(wsb + o);
    const bool f32ok = (o + (size_t)N_NODES * HC * 4) <= ws_size;

    hipMemsetAsync(count, 0, 2 * (size_t)N_NODES * sizeof(int), stream);

    k_ntm<<<(N_NODES + 63) / 64, 256, 0, stream>>>(x, W_l, b_l, W_r, b_r, xl_t, xr_t);
    k_permw<<<1, 256, 0, stream>>>(W1, b1, gamma, beta, bias_gat, W2,
                                   W1p, b1p, gammap, betap, biasgp, W2p);
    k_hist<<<(N_EDGES + 255) / 256, 256, 0, stream>>>(ei, count);
    k_scan<<<1, 1024, 0, stream>>>(count, off);
    k_scatter<<<(N_EDGES + 255) / 256, 256, 0, stream>>>(ei, off, cursor, csr_src, eid_csr);
    if (f32ok) {
        k_edgeagg<true><<<EDGE_BLOCKS, 256, 0, stream>>>(off, csr_src, eid_csr, edge_attr,
                                                         W_e, att, xl_t, xr_t, zs_g);
        k_post<true><<<N_NODES / 16, 256, 0, stream>>>(zs_g, x, biasgp,
                                                       W1p, b1p, gammap, betap, W2p, b2, out);
    } else {
        k_edgeagg<false><<<EDGE_BLOCKS, 256, 0, stream>>>(off, csr_src, eid_csr, edge_attr,
                                                          W_e, att, xl_t, xr_t, zs_g);
        k_post<false><<<N_NODES / 16, 256, 0, stream>>>(zs_g, x, biasgp,
                                                        W1p, b1p, gammap, betap, W2p, b2, out);
    }
}

// Round 21
// 528.268 us; speedup vs baseline: 3.9652x; 1.0616x over previous
//
#include <hip/hip_runtime.h>
#include <math.h>

#define N_NODES 50000
#define N_EDGES 800000
#define HID 64
#define HEADS 4
#define HC 256
#define NEG_SLOPE 0.2f
#define LN_EPS 1e-5f
#define EDGE_BLOCKS 2048   // persistent-wave grid for k_edgeagg (8192 waves)

typedef __attribute__((ext_vector_type(8))) short bf16x8;
typedef __attribute__((ext_vector_type(8))) unsigned short u16x8;
typedef __attribute__((ext_vector_type(4))) float f32x4;

__device__ __forceinline__ float bf2f(unsigned short u) {
    return __uint_as_float(((unsigned int)u) << 16);
}
__device__ __forceinline__ unsigned short f2bf(float f) {
    unsigned int u = __float_as_uint(f);
    u = (u + 0x7fffu + ((u >> 16) & 1u)) >> 16;   // RNE
    return (unsigned short)u;
}
__device__ __forceinline__ float fast_tanh(float v) {
    const float c = fminf(fmaxf(v, -15.f), 15.f);
    const float e = __expf(2.f * c);
    return 1.f - 2.f / (e + 1.f);
}
__device__ __forceinline__ bf16x8 pack_bf8(float4 a, float4 b) {
    u16x8 r;
    r[0] = f2bf(a.x); r[1] = f2bf(a.y); r[2] = f2bf(a.z); r[3] = f2bf(a.w);
    r[4] = f2bf(b.x); r[5] = f2bf(b.y); r[6] = f2bf(b.z); r[7] = f2bf(b.w);
    return __builtin_bit_cast(bf16x8, r);
}

// ---------------- K1: MFMA node transform (64 nodes/block, 4 waves) --------
__global__ __launch_bounds__(256) void k_ntm(
    const float* __restrict__ x,
    const float* __restrict__ W_l, const float* __restrict__ b_l,
    const float* __restrict__ W_r, const float* __restrict__ b_r,
    unsigned short* __restrict__ xl_t, unsigned short* __restrict__ xr_t)
{
    __shared__ unsigned short wl_s[2][16][64][8];   // 32 KB
    __shared__ unsigned short wr_s[2][16][64][8];   // 32 KB
    const int t = threadIdx.x, lane = t & 63, wv = t >> 6;
    const int arow = lane & 15, koct = lane >> 4;

    for (int i = t; i < 2048; i += 256) {
        const int ks = i >> 10, nt = (i >> 6) & 15, ls = i & 63;
        const int col = nt * 16 + (ls & 15);
        const int kb = ks * 32 + (ls >> 4) * 8;
        unsigned short a[8], b[8];
#pragma unroll
        for (int j = 0; j < 8; j++) {
            a[j] = f2bf(W_l[(kb + j) * 256 + col]);
            b[j] = f2bf(W_r[(kb + j) * 256 + col]);
        }
        *(ushort4*)&wl_s[ks][nt][ls][0] = make_ushort4(a[0], a[1], a[2], a[3]);
        *(ushort4*)&wl_s[ks][nt][ls][4] = make_ushort4(a[4], a[5], a[6], a[7]);
        *(ushort4*)&wr_s[ks][nt][ls][0] = make_ushort4(b[0], b[1], b[2], b[3]);
        *(ushort4*)&wr_s[ks][nt][ls][4] = make_ushort4(b[4], b[5], b[6], b[7]);
    }
    __syncthreads();

    const int n0w = blockIdx.x * 64 + wv * 16;
    if (n0w >= N_NODES) return;

    const float* xrow = x + (size_t)(n0w + arow) * 64;
    const bf16x8 af0 = pack_bf8(*(const float4*)(xrow + koct * 8),
                                *(const float4*)(xrow + koct * 8 + 4));
    const bf16x8 af1 = pack_bf8(*(const float4*)(xrow + 32 + koct * 8),
                                *(const float4*)(xrow + 32 + koct * 8 + 4));

    float acc[4][16];
#pragma unroll
    for (int nt = 0; nt < 16; nt++) {
        const float bv = b_l[nt * 16 + arow];
        f32x4 d = {bv, bv, bv, bv};
        d = __builtin_amdgcn_mfma_f32_16x16x32_bf16(af0, *(const bf16x8*)&wl_s[0][nt][lane][0], d, 0, 0, 0);
        d = __builtin_amdgcn_mfma_f32_16x16x32_bf16(af1, *(const bf16x8*)&wl_s[1][nt][lane][0], d, 0, 0, 0);
#pragma unroll
        for (int r = 0; r < 4; r++) acc[r][nt] = d[r];
    }
#pragma unroll
    for (int r = 0; r < 4; r++) {
        u16x8 lo, hi;
#pragma unroll
        for (int j = 0; j < 8; j++) { lo[j] = f2bf(acc[r][j]); hi[j] = f2bf(acc[r][j + 8]); }
        unsigned short* dst = xl_t + (size_t)(n0w + koct * 4 + r) * 256 + arow * 16;
        *(u16x8*)dst = lo;
        *(u16x8*)(dst + 8) = hi;
    }
#pragma unroll
    for (int nt = 0; nt < 16; nt++) {
        const float bv = b_r[nt * 16 + arow];
        f32x4 d = {bv, bv, bv, bv};
        d = __builtin_amdgcn_mfma_f32_16x16x32_bf16(af0, *(const bf16x8*)&wr_s[0][nt][lane][0], d, 0, 0, 0);
        d = __builtin_amdgcn_mfma_f32_16x16x32_bf16(af1, *(const bf16x8*)&wr_s[1][nt][lane][0], d, 0, 0, 0);
#pragma unroll
        for (int r = 0; r < 4; r++) acc[r][nt] = d[r];
    }
#pragma unroll
    for (int r = 0; r < 4; r++) {
        u16x8 lo, hi;
#pragma unroll
        for (int j = 0; j < 8; j++) { lo[j] = f2bf(acc[r][j]); hi[j] = f2bf(acc[r][j + 8]); }
        unsigned short* dst = xr_t + (size_t)(n0w + koct * 4 + r) * 256 + arow * 16;
        *(u16x8*)dst = lo;
        *(u16x8*)(dst + 8) = hi;
    }
}

// ---------------- K1b: permute channel-indexed weights to pos-space --------
__global__ __launch_bounds__(256) void k_permw(
    const float* __restrict__ W1, const float* __restrict__ b1,
    const float* __restrict__ gamma, const float* __restrict__ beta,
    const float* __restrict__ bias_gat, const float* __restrict__ W2,
    float* __restrict__ W1p, float* __restrict__ b1p,
    float* __restrict__ gammap, float* __restrict__ betap,
    float* __restrict__ biasgp, float* __restrict__ W2p)
{
    const int c = threadIdx.x;
    const int pos = (c & 15) * 16 + (c >> 4);
    for (int k = 0; k < 64; k++) W1p[k * 256 + pos] = W1[k * 256 + c];
    b1p[pos] = b1[c];
    gammap[pos] = gamma[c];
    betap[pos] = beta[c];
    biasgp[pos] = bias_gat[c];
    for (int j = 0; j < 64; j++) W2p[pos * 64 + j] = W2[c * 64 + j];
}

// ---------------- K2: histogram of dst ------------------------------------
__global__ __launch_bounds__(256) void k_hist(const int* __restrict__ ei, int* __restrict__ count)
{
    const int e = blockIdx.x * 256 + threadIdx.x;
    if (e < N_EDGES) atomicAdd(&count[ei[N_EDGES + e]], 1);
}

// ---------------- K3: exclusive scan (single block) ------------------------
__global__ __launch_bounds__(1024) void k_scan(const int* __restrict__ count, int* __restrict__ off)
{
    __shared__ int wsum[16];
    __shared__ int s_carry;
    const int t = threadIdx.x, lane = t & 63, wv = t >> 6;
    if (t == 0) s_carry = 0;
    __syncthreads();
    for (int base = 0; base < N_NODES; base += 8192) {
        const int idx0 = base + t * 8;
        int v[8];
#pragma unroll
        for (int j = 0; j < 8; j++) { int i = idx0 + j; v[j] = (i < N_NODES) ? count[i] : 0; }
#pragma unroll
        for (int j = 1; j < 8; j++) v[j] += v[j - 1];
        const int tot = v[7];
        int sc = tot;
#pragma unroll
        for (int s = 1; s < 64; s <<= 1) { int o = __shfl_up(sc, s, 64); if (lane >= s) sc += o; }
        if (lane == 63) wsum[wv] = sc;
        __syncthreads();
        const int carry = s_carry;
        int woff = 0;
        for (int u = 0; u < wv; u++) woff += wsum[u];
        const int ebase = carry + woff + (sc - tot);
#pragma unroll
        for (int j = 0; j < 8; j++) {
            int i = idx0 + j;
            if (i < N_NODES) off[i] = ebase + (j ? v[j - 1] : 0);
        }
        __syncthreads();
        if (t == 0) { int tt = 0; for (int u = 0; u < 16; u++) tt += wsum[u]; s_carry = carry + tt; }
        __syncthreads();
    }
    if (threadIdx.x == 0) off[N_NODES] = s_carry;
}

// ---------------- K4: scatter src + eid into CSR (index-only, 4B) ----------
__global__ __launch_bounds__(256) void k_scatter(
    const int* __restrict__ ei, const int* __restrict__ off, int* __restrict__ cursor,
    int* __restrict__ csr_src, int* __restrict__ eid_csr)
{
    const int e = blockIdx.x * 256 + threadIdx.x;
    if (e < N_EDGES) {
        const int s = ei[e];
        const int d = ei[N_EDGES + e];
        const int pos = off[d] + atomicAdd(&cursor[d], 1);
        csr_src[pos] = s;
        eid_csr[pos] = e;
    }
}

// ---------------- K5: edge+aggregate, persistent waves, deep pipeline ------
template<bool F32>
__global__ __launch_bounds__(256) void k_edgeagg(
    const int* __restrict__ off, const int* __restrict__ csr_src,
    const int* __restrict__ eid_csr, const float* __restrict__ edge_attr,
    const float* __restrict__ W_e, const float* __restrict__ att,
    const unsigned short* __restrict__ xl_t, const unsigned short* __restrict__ xr_t,
    void* __restrict__ zs_g)
{
    __shared__ unsigned short bfrag_s[16][64][8];   // 16 KB, only LDS

    const int t = threadIdx.x;
    const int lane = t & 63, wv = t >> 6;
    const int arow = lane & 15, koct = lane >> 4;

    for (int i = t; i < 1024; i += 256) {
        const int nt = i >> 6, ls = i & 63;
        const int col = nt * 16 + (ls & 15);
        const int kb = (ls >> 4) * 8;
        unsigned short tmp[8];
#pragma unroll
        for (int j = 0; j < 8; j++) tmp[j] = f2bf(W_e[(kb + j) * 256 + col]);
        *(ushort4*)&bfrag_s[nt][ls][0] = make_ushort4(tmp[0], tmp[1], tmp[2], tmp[3]);
        *(ushort4*)&bfrag_s[nt][ls][4] = make_ushort4(tmp[4], tmp[5], tmp[6], tmp[7]);
    }
    __syncthreads();

    float attLf[8], attHf[8];
#pragma unroll
    for (int j = 0; j < 8; j++) {
        attLf[j] = att[j * 16 + arow];
        attHf[j] = att[(j + 8) * 16 + arow];
    }

    const int STRIDE = EDGE_BLOCKS * 4;
    int node = blockIdx.x * 4 + wv;
    if (node >= N_NODES) return;

    int lo = off[node], hi = off[node + 1];
    u16x8 xrl = *(const u16x8*)(xr_t + (size_t)node * 256 + arow * 16);
    u16x8 xrh = *(const u16x8*)(xr_t + (size_t)node * 256 + arow * 16 + 8);
    while (hi <= lo) {
        if (F32) *(float4*)((float*)zs_g + (size_t)node * 256 + arow * 16 + koct * 4) = make_float4(0.f, 0.f, 0.f, 0.f);
        else *(ushort4*)((unsigned short*)zs_g + (size_t)node * 256 + arow * 16 + koct * 4) = make_ushort4(0, 0, 0, 0);
        node += STRIDE;
        if (node >= N_NODES) return;
        lo = off[node]; hi = off[node + 1];
        xrl = *(const u16x8*)(xr_t + (size_t)node * 256 + arow * 16);
        xrh = *(const u16x8*)(xr_t + (size_t)node * 256 + arow * 16 + 8);
    }
    int svbase = lo;
    int svall = csr_src[min(svbase + lane, hi - 1)];
    int evall = eid_csr[min(svbase + lane, hi - 1)];

    int nnode = node + STRIDE;
    bool nvalid = nnode < N_NODES;
    int nlo = 0, nhi = 0, nsvall = 0, nevall = 0;
    u16x8 nxrl = xrl, nxrh = xrh;
    if (nvalid) {
        nlo = off[nnode]; nhi = off[nnode + 1];
        nxrl = *(const u16x8*)(xr_t + (size_t)nnode * 256 + arow * 16);
        nxrh = *(const u16x8*)(xr_t + (size_t)nnode * 256 + arow * 16 + 8);
        if (nhi > nlo) {
            nsvall = csr_src[min(nlo + lane, nhi - 1)];
            nevall = eid_csr[min(nlo + lane, nhi - 1)];
        }
    }
    int p0 = lo;
    bf16x8 af;
    u16x8 xlo[4], xhi[4];
    {
        const int eid0 = __shfl(evall, arow, 64);
        const float* ap = edge_attr + (size_t)eid0 * 32 + koct * 8;
        af = pack_bf8(*(const float4*)ap, *(const float4*)(ap + 4));
#pragma unroll
        for (int r = 0; r < 4; r++) {
            const int sr = __shfl(svall, koct * 4 + r, 64);
            const unsigned short* bp = xl_t + (size_t)sr * 256 + arow * 16;
            xlo[r] = *(const u16x8*)bp;
            xhi[r] = *(const u16x8*)(bp + 8);
        }
    }

    float g[16];
#pragma unroll
    for (int i = 0; i < 16; i++) g[i] = 0.f;
    float dsum[4] = {0.f, 0.f, 0.f, 0.f};

    for (;;) {
        const bool last = (p0 + 16 >= hi);
        bool uvalid;
        int up0;
        if (!last) { uvalid = true; up0 = p0 + 16; }
        else {
            while (nvalid && nlo >= nhi) {
                if (F32) *(float4*)((float*)zs_g + (size_t)nnode * 256 + arow * 16 + koct * 4) = make_float4(0.f, 0.f, 0.f, 0.f);
                else *(ushort4*)((unsigned short*)zs_g + (size_t)nnode * 256 + arow * 16 + koct * 4) = make_ushort4(0, 0, 0, 0);
                nnode += STRIDE;
                nvalid = nnode < N_NODES;
                if (nvalid) {
                    nlo = off[nnode]; nhi = off[nnode + 1];
                    nxrl = *(const u16x8*)(xr_t + (size_t)nnode * 256 + arow * 16);
                    nxrh = *(const u16x8*)(xr_t + (size_t)nnode * 256 + arow * 16 + 8);
                    if (nhi > nlo) {
                        nsvall = csr_src[min(nlo + lane, nhi - 1)];
                        nevall = eid_csr[min(nlo + lane, nhi - 1)];
                    }
                }
            }
            uvalid = nvalid; up0 = nlo;
        }
        float4 uA0 = make_float4(0.f, 0.f, 0.f, 0.f), uA1 = uA0;
        if (uvalid) {
            const int ubase = last ? 0 : (up0 - svbase);
            const int uev = last ? nevall : evall;
            const int ueid = __shfl(uev, ubase + arow, 64);
            const float* ap = edge_attr + (size_t)ueid * 32 + koct * 8;
            uA0 = *(const float4*)ap;
            uA1 = *(const float4*)(ap + 4);
        }

        float s_[4][4];
#pragma unroll
        for (int r = 0; r < 4; r++)
#pragma unroll
            for (int h = 0; h < 4; h++) s_[r][h] = 0.f;

#pragma unroll
        for (int nt = 0; nt < 8; nt++) {
            const bf16x8 bfr = *(const bf16x8*)&bfrag_s[nt][lane][0];
            const float xrv = bf2f((unsigned short)xrl[nt]);
            f32x4 dacc = {xrv, xrv, xrv, xrv};
            dacc = __builtin_amdgcn_mfma_f32_16x16x32_bf16(af, bfr, dacc, 0, 0, 0);
            const float atv = attLf[nt];
            const int h = nt >> 2;
#pragma unroll
            for (int r = 0; r < 4; r++) {
                const float mm = dacc[r] + bf2f((unsigned short)xlo[r][nt]);
                const float lk = fmaxf(mm, NEG_SLOPE * mm);
                s_[r][h] = fmaf(atv, lk, s_[r][h]);
            }
        }
        u16x8 uxlo[4], uxhi[4];
        if (uvalid) {
            const int ubase = last ? 0 : (up0 - svbase);
            const int usrcv = last ? nsvall : svall;
#pragma unroll
            for (int r = 0; r < 4; r++) {
                const int sr = __shfl(usrcv, ubase + koct * 4 + r, 64);
                const unsigned short* bp = xl_t + (size_t)sr * 256 + arow * 16;
                uxlo[r] = *(const u16x8*)bp;
                uxhi[r] = *(const u16x8*)(bp + 8);
            }
        } else {
#pragma unroll
            for (int r = 0; r < 4; r++) { uxlo[r] = xlo[r]; uxhi[r] = xhi[r]; }
        }
#pragma unroll
        for (int n2 = 0; n2 < 8; n2++) {
            const int nt = n2 + 8;
            const bf16x8 bfr = *(const bf16x8*)&bfrag_s[nt][lane][0];
            const float xrv = bf2f((unsigned short)xrh[n2]);
            f32x4 dacc = {xrv, xrv, xrv, xrv};
            dacc = __builtin_amdgcn_mfma_f32_16x16x32_bf16(af, bfr, dacc, 0, 0, 0);
            const float atv = attHf[n2];
            const int h = nt >> 2;
#pragma unroll
            for (int r = 0; r < 4; r++) {
                const float mm = dacc[r] + bf2f((unsigned short)xhi[r][n2]);
                const float lk = fmaxf(mm, NEG_SLOPE * mm);
                s_[r][h] = fmaf(atv, lk, s_[r][h]);
            }
        }
#pragma unroll
        for (int r = 0; r < 4; r++)
#pragma unroll
            for (int h = 0; h < 4; h++) {
                float v = s_[r][h];
                v += __shfl_xor(v, 1, 64);
                v += __shfl_xor(v, 2, 64);
                v += __shfl_xor(v, 4, 64);
                v += __shfl_xor(v, 8, 64);
                s_[r][h] = v;
            }
#pragma unroll
        for (int h = 0; h < 4; h++) {
            float w4[4];
#pragma unroll
            for (int r = 0; r < 4; r++) {
                const bool ok = (p0 + koct * 4 + r) < hi;
                w4[r] = ok ? __expf(fminf(s_[r][h], 60.f)) : 0.f;
            }
            dsum[h] += (w4[0] + w4[1]) + (w4[2] + w4[3]);
#pragma unroll
            for (int q = 0; q < 4; q++) {
                const int nt = h * 4 + q;
                float acc = g[nt];
#pragma unroll
                for (int r = 0; r < 4; r++) {
                    const float xv = bf2f((unsigned short)(nt < 8 ? xlo[r][nt & 7] : xhi[r][nt & 7]));
                    acc = fmaf(w4[r], xv, acc);
                }
                g[nt] = acc;
            }
        }

        if (last) {
#pragma unroll
            for (int i = 0; i < 16; i++) {
                float v = g[i];
                v += __shfl_xor(v, 16, 64);
                v += __shfl_xor(v, 32, 64);
                g[i] = v;
            }
#pragma unroll
            for (int h = 0; h < 4; h++) {
                float v = dsum[h];
                v += __shfl_xor(v, 16, 64);
                v += __shfl_xor(v, 32, 64);
                dsum[h] = v;
            }
            const float inv = 1.f / (dsum[koct] + 1e-16f);
            if (F32) {
                *(float4*)((float*)zs_g + (size_t)node * 256 + arow * 16 + koct * 4) =
                    make_float4(g[koct * 4] * inv, g[koct * 4 + 1] * inv,
                                g[koct * 4 + 2] * inv, g[koct * 4 + 3] * inv);
            } else {
                *(ushort4*)((unsigned short*)zs_g + (size_t)node * 256 + arow * 16 + koct * 4) =
                    make_ushort4(f2bf(g[koct * 4] * inv), f2bf(g[koct * 4 + 1] * inv),
                                 f2bf(g[koct * 4 + 2] * inv), f2bf(g[koct * 4 + 3] * inv));
            }
            if (!uvalid) return;
            node = nnode; lo = nlo; hi = nhi; xrl = nxrl; xrh = nxrh;
            svbase = nlo; svall = nsvall; evall = nevall;
#pragma unroll
            for (int i = 0; i < 16; i++) g[i] = 0.f;
#pragma unroll
            for (int h = 0; h < 4; h++) dsum[h] = 0.f;
            nnode += STRIDE;
            nvalid = nnode < N_NODES;
            if (nvalid) {
                nlo = off[nnode]; nhi = off[nnode + 1];
                nxrl = *(const u16x8*)(xr_t + (size_t)nnode * 256 + arow * 16);
                nxrh = *(const u16x8*)(xr_t + (size_t)nnode * 256 + arow * 16 + 8);
                if (nhi > nlo) {
                    nsvall = csr_src[min(nlo + lane, nhi - 1)];
                    nevall = eid_csr[min(nlo + lane, nhi - 1)];
                }
            }
        }
        p0 = up0;
        af = pack_bf8(uA0, uA1);
#pragma unroll
        for (int r = 0; r < 4; r++) { xlo[r] = uxlo[r]; xhi[r] = uxhi[r]; }
        if (p0 - svbase >= 32) {
            svbase = p0;
            svall = csr_src[min(svbase + lane, hi - 1)];
            evall = eid_csr[min(svbase + lane, hi - 1)];
        }
    }
}

// ---------------- K6: MFMA epilogue (64 nodes/block, 4 waves x 16 nodes) ---
// GEMM1 B-frag tile nt covers pos columns {(ls&15)*16 + nt} so D lane-col
// arow maps to pos = arow*16+nt (matches zs_g/bias/gamma/zsh indexing).
template<bool F32>
__global__ __launch_bounds__(256) void k_post(
    const void* __restrict__ zs_g, const float* __restrict__ x,
    const float* __restrict__ biasgp,
    const float* __restrict__ W1p, const float* __restrict__ b1p,
    const float* __restrict__ gammap, const float* __restrict__ betap,
    const float* __restrict__ W2p, const float* __restrict__ b2,
    float* __restrict__ out)
{
    __shared__ unsigned short wf[16384];        // 32 KB: w1f[2][16][64][8] / w2f[8][4][64][8]
    __shared__ unsigned short zsh[64][272];     // 34 KB (pad 16 -> aligned, banks spread)
    __shared__ float outsh[64][64];             // 16 KB

    const int t = threadIdx.x, lane = t & 63, wv = t >> 6;
    const int arow = lane & 15, koct = lane >> 4;
    const int n0 = blockIdx.x * 64;
    const int nw = n0 + wv * 16;

    // ---- stage W1 frags: tile nt covers pos columns (ls&15)*16 + nt ----
    for (int i = t; i < 2048; i += 256) {
        const int ks = i >> 10, nt = (i >> 6) & 15, ls = i & 63;
        const int col = (ls & 15) * 16 + nt;
        const int kb = ks * 32 + (ls >> 4) * 8;
        unsigned short a[8];
#pragma unroll
        for (int j = 0; j < 8; j++) a[j] = f2bf(W1p[(kb + j) * 256 + col]);
        *(ushort4*)&wf[i * 8]     = make_ushort4(a[0], a[1], a[2], a[3]);
        *(ushort4*)&wf[i * 8 + 4] = make_ushort4(a[4], a[5], a[6], a[7]);
    }
    __syncthreads();

    // ---- GEMM1: A = x rows ----
    const int xn = min(nw + arow, N_NODES - 1);
    const float* xrow = x + (size_t)xn * 64;
    const bf16x8 af0 = pack_bf8(*(const float4*)(xrow + koct * 8),
                                *(const float4*)(xrow + koct * 8 + 4));
    const bf16x8 af1 = pack_bf8(*(const float4*)(xrow + 32 + koct * 8),
                                *(const float4*)(xrow + 32 + koct * 8 + 4));

    float z[4][16];   // z[r][nt] = pos (arow*16 + nt) of node nw + koct*4 + r
#pragma unroll
    for (int nt = 0; nt < 16; nt++) {
        const float bv = b1p[arow * 16 + nt];
        f32x4 d = {bv, bv, bv, bv};
        d = __builtin_amdgcn_mfma_f32_16x16x32_bf16(af0, *(const bf16x8*)&wf[(0 * 16 + nt) * 512 + lane * 8], d, 0, 0, 0);
        d = __builtin_amdgcn_mfma_f32_16x16x32_bf16(af1, *(const bf16x8*)&wf[(1 * 16 + nt) * 512 + lane * 8], d, 0, 0, 0);
#pragma unroll
        for (int r = 0; r < 4; r++) z[r][nt] = d[r];
    }
    // ---- z = tanh(a1) + g + bias_gat (pos-major g read: contiguous 16) ----
#pragma unroll
    for (int r = 0; r < 4; r++) {
        const int nd = min(nw + koct * 4 + r, N_NODES - 1);
        float gv[16];
        if (F32) {
            const float* gp = (const float*)zs_g + (size_t)nd * 256 + arow * 16;
#pragma unroll
            for (int i4 = 0; i4 < 4; i4++) {
                const float4 v = *(const float4*)(gp + i4 * 4);
                gv[i4 * 4] = v.x; gv[i4 * 4 + 1] = v.y; gv[i4 * 4 + 2] = v.z; gv[i4 * 4 + 3] = v.w;
            }
        } else {
            const unsigned short* gp = (const unsigned short*)zs_g + (size_t)nd * 256 + arow * 16;
            const u16x8 a = *(const u16x8*)gp;
            const u16x8 b = *(const u16x8*)(gp + 8);
#pragma unroll
            for (int j = 0; j < 8; j++) { gv[j] = bf2f((unsigned short)a[j]); gv[j + 8] = bf2f((unsigned short)b[j]); }
        }
#pragma unroll
        for (int nt = 0; nt < 16; nt++)
            z[r][nt] = fast_tanh(z[r][nt]) + gv[nt] + biasgp[arow * 16 + nt];
    }
    // ---- LayerNorm: sum over nt then butterfly over arow lanes ----
#pragma unroll
    for (int r = 0; r < 4; r++) {
        float s = 0.f, q = 0.f;
#pragma unroll
        for (int nt = 0; nt < 16; nt++) { s += z[r][nt]; q = fmaf(z[r][nt], z[r][nt], q); }
        s += __shfl_xor(s, 1, 64); q += __shfl_xor(q, 1, 64);
        s += __shfl_xor(s, 2, 64); q += __shfl_xor(q, 2, 64);
        s += __shfl_xor(s, 4, 64); q += __shfl_xor(q, 4, 64);
        s += __shfl_xor(s, 8, 64); q += __shfl_xor(q, 8, 64);
        const float mu = s * (1.f / 256.f);
        const float var = q * (1.f / 256.f) - mu * mu;
        const float ivn = rsqrtf(var + LN_EPS);
        u16x8 lo, hi;
#pragma unroll
        for (int nt = 0; nt < 16; nt++) {
            const float zn = (z[r][nt] - mu) * ivn * gammap[arow * 16 + nt] + betap[arow * 16 + nt];
            if (nt < 8) lo[nt] = f2bf(zn); else hi[nt - 8] = f2bf(zn);
        }
        unsigned short* dst = &zsh[wv * 16 + koct * 4 + r][arow * 16];
        *(u16x8*)dst = lo;
        *(u16x8*)(dst + 8) = hi;
    }
    __syncthreads();
    // ---- stage W2 frags (overwrite W1 frags) ----
    for (int i = t; i < 2048; i += 256) {
        const int kb = i >> 8, ct = (i >> 6) & 3, ls = i & 63;
        const int col = ct * 16 + (ls & 15);
        const int k0 = kb * 32 + (ls >> 4) * 8;
        unsigned short a[8];
#pragma unroll
        for (int j = 0; j < 8; j++) a[j] = f2bf(W2p[(k0 + j) * 64 + col]);
        *(ushort4*)&wf[i * 8]     = make_ushort4(a[0], a[1], a[2], a[3]);
        *(ushort4*)&wf[i * 8 + 4] = make_ushort4(a[4], a[5], a[6], a[7]);
    }
    __syncthreads();
    // ---- GEMM2: A = zsh rows (node=l&15), K=256 over pos ----
    f32x4 acc2[4];
#pragma unroll
    for (int ct = 0; ct < 4; ct++) {
        const float bv = b2[ct * 16 + arow];
        acc2[ct][0] = bv; acc2[ct][1] = bv; acc2[ct][2] = bv; acc2[ct][3] = bv;
    }
#pragma unroll
    for (int kb = 0; kb < 8; kb++) {
        const bf16x8 a = *(const bf16x8*)&zsh[wv * 16 + arow][kb * 32 + koct * 8];
#pragma unroll
        for (int ct = 0; ct < 4; ct++)
            acc2[ct] = __builtin_amdgcn_mfma_f32_16x16x32_bf16(
                a, *(const bf16x8*)&wf[((kb * 4 + ct) * 64 + lane) * 8], acc2[ct], 0, 0, 0);
    }
#pragma unroll
    for (int ct = 0; ct < 4; ct++)
#pragma unroll
        for (int r = 0; r < 4; r++)
            outsh[wv * 16 + koct * 4 + r][ct * 16 + arow] = fast_tanh(acc2[ct][r]);
    __syncthreads();
    // ---- coalesced store ----
    for (int i = t; i < 4096; i += 256) {
        const int row = i >> 6;
        if (n0 + row < N_NODES)
            out[(size_t)(n0 + row) * 64 + (i & 63)] = outsh[row][i & 63];
    }
}

// ---------------- launcher --------------------------------------------------
extern "C" void kernel_launch(void* const* d_in, const int* in_sizes, int n_in,
                              void* d_out, int out_size, void* d_ws, size_t ws_size,
                              hipStream_t stream)
{
    const float* x         = (const float*)d_in[0];
    const int*   ei        = (const int*)d_in[1];
    const float* edge_attr = (const float*)d_in[2];
    const float* W_l       = (const float*)d_in[3];
    const float* b_l       = (const float*)d_in[4];
    const float* W_r       = (const float*)d_in[5];
    const float* b_r       = (const float*)d_in[6];
    const float* W_e       = (const float*)d_in[7];
    const float* att       = (const float*)d_in[8];
    const float* bias_gat  = (const float*)d_in[9];
    const float* W1        = (const float*)d_in[10];
    const float* b1        = (const float*)d_in[11];
    const float* gamma     = (const float*)d_in[12];
    const float* beta      = (const float*)d_in[13];
    const float* W2        = (const float*)d_in[14];
    const float* b2        = (const float*)d_in[15];
    float* out = (float*)d_out;

    char* wsb = (char*)d_ws;
    size_t o = 0;
    unsigned short* xl_t   = (unsigned short*)(wsb + o);  o += (size_t)N_NODES * HC * 2;
    unsigned short* xr_t   = (unsigned short*)(wsb + o);  o += (size_t)N_NODES * HC * 2;
    int* csr_src           = (int*)(wsb + o);             o += (size_t)N_EDGES * 4;
    int* eid_csr           = (int*)(wsb + o);             o += (size_t)N_EDGES * 4;
    int* count             = (int*)(wsb + o);             o += (size_t)N_NODES * 4;
    int* cursor            = (int*)(wsb + o);             o += (size_t)N_NODES * 4;
    int* off               = (int*)(wsb + o);             o += (size_t)(N_NODES + 1) * 4;
    float* W1p             = (float*)(wsb + o);           o += 64 * 256 * 4;
    float* W2p             = (float*)(wsb + o);           o += 256 * 64 * 4;
    float* b1p             = (float*)(wsb + o);           o += 256 * 4;
    float* gammap          = (float*)(wsb + o);           o += 256 * 4;
    float* betap           = (float*)(wsb + o);           o += 256 * 4;
    float* biasgp          = (float*)(wsb + o);           o += 256 * 4;
    o = (o + 255) & ~(size_t)255;
    void* zs_g             = (void*)(wsb + o);
    const bool f32ok = (o + (size_t)N_NODES * HC * 4) <= ws_size;

    hipMemsetAsync(count, 0, 2 * (size_t)N_NODES * sizeof(int), stream);

    k_ntm<<<(N_NODES + 63) / 64, 256, 0, stream>>>(x, W_l, b_l, W_r, b_r, xl_t, xr_t);
    k_permw<<<1, 256, 0, stream>>>(W1, b1, gamma, beta, bias_gat, W2,
                                   W1p, b1p, gammap, betap, biasgp, W2p);
    k_hist<<<(N_EDGES + 255) / 256, 256, 0, stream>>>(ei, count);
    k_scan<<<1, 1024, 0, stream>>>(count, off);
    k_scatter<<<(N_EDGES + 255) / 256, 256, 0, stream>>>(ei, off, cursor, csr_src, eid_csr);
    if (f32ok) {
        k_edgeagg<true><<<EDGE_BLOCKS, 256, 0, stream>>>(off, csr_src, eid_csr, edge_attr,
                                                         W_e, att, xl_t, xr_t, zs_g);
        k_post<true><<<(N_NODES + 63) / 64, 256, 0, stream>>>(zs_g, x, biasgp,
                                                              W1p, b1p, gammap, betap, W2p, b2, out);
    } else {
        k_edgeagg<false><<<EDGE_BLOCKS, 256, 0, stream>>>(off, csr_src, eid_csr, edge_attr,
                                                          W_e, att, xl_t, xr_t, zs_g);
        k_post<false><<<(N_NODES + 63) / 64, 256, 0, stream>>>(zs_g, x, biasgp,
                                                               W1p, b1p, gammap, betap, W2p, b2, out);
    }
}